// Round 4
// baseline (14462.691 us; speedup 1.0000x reference)
//
#include <hip/hip_runtime.h>
#include <math.h>

#define TS_ 19   // T-1 decode steps
#define NBLK 256
#define NTHR 512

typedef float f32x4 __attribute__((ext_vector_type(4)));
typedef short s16x8 __attribute__((ext_vector_type(8)));

__device__ __forceinline__ float sigmoidf_(float x) { return 1.f / (1.f + __expf(-x)); }

__device__ __forceinline__ float fast_tanh(float x) {
    float ax = fabsf(x);
    float e = __expf(-2.f * ax);
    float r = (1.f - e) * __builtin_amdgcn_rcpf(1.f + e);
    return copysignf(r, x);
}

__device__ __forceinline__ unsigned short f2b(float x) {
    union { float f; unsigned u; } v; v.f = x;
    unsigned r = v.u + 0x7fffu + ((v.u >> 16) & 1u);
    return (unsigned short)(r >> 16);
}
__device__ __forceinline__ float b2f(unsigned short u) {
    union { unsigned u; float f; } v; v.u = ((unsigned)u) << 16; return v.f;
}

#define MFMA(a, b, c) __builtin_amdgcn_mfma_f32_16x16x32_bf16((a), (b), (c), 0, 0, 0)

__device__ __forceinline__ f32x4 zero4() { return (f32x4){0.f, 0.f, 0.f, 0.f}; }

// wave 16x16 GEMM accumulate helper: A rows / B rows both bf16, contiguous in k.
__device__ __forceinline__ f32x4 wg16(const unsigned short* ap, const unsigned short* bp,
                                      int nk, f32x4 acc) {
#pragma unroll 4
    for (int k = 0; k < nk; k += 32)
        acc = MFMA(*(const s16x8*)(ap + k), *(const s16x8*)(bp + k), acc);
    return acc;
}

// ---------------- device-wide barrier (monotonic counter) ----------------
__device__ __forceinline__ void gbar(unsigned* cnt, unsigned target) {
    __threadfence();
    __syncthreads();
    if (threadIdx.x == 0) {
        __hip_atomic_fetch_add(cnt, 1u, __ATOMIC_RELEASE, __HIP_MEMORY_SCOPE_AGENT);
        while (__hip_atomic_load(cnt, __ATOMIC_ACQUIRE, __HIP_MEMORY_SCOPE_AGENT) < target)
            __builtin_amdgcn_s_sleep(1);
    }
    __syncthreads();
    __threadfence();
}

// ---------------- prep kernels ----------------
__global__ __launch_bounds__(256) void k_cvt(const float* __restrict__ in,
                                             unsigned short* __restrict__ out, long n) {
    long i = ((long)blockIdx.x * 256 + threadIdx.x) * 4;
    long stride = (long)gridDim.x * 1024;
    for (; i < n; i += stride) {
        float4 v = *(const float4*)(in + i);
        ushort4 o = { f2b(v.x), f2b(v.y), f2b(v.z), f2b(v.w) };
        *(ushort4*)(out + i) = o;
    }
}

__global__ void k_tcvt(const float* __restrict__ in, unsigned short* __restrict__ out) {
    __shared__ float tile[32][33];
    int bx = blockIdx.x * 32, by = blockIdx.y * 32;
    int x = threadIdx.x, y0 = threadIdx.y;
    for (int yy = y0; yy < 32; yy += 8) tile[yy][x] = in[(by + yy) * 1024 + bx + x];
    __syncthreads();
    for (int yy = y0; yy < 32; yy += 8) out[(bx + yy) * 1024 + by + x] = f2b(tile[x][yy]);
}

__global__ __launch_bounds__(256) void k_yemb(const int* __restrict__ y,
                                              const float* __restrict__ embW,
                                              unsigned short* __restrict__ xc) {
    int t = blockIdx.x >> 6, b = blockIdx.x & 63;
    int row = y[t * 64 + b];
    const float* src = embW + (long)row * 512;
    unsigned short* dst = xc + (long)(t * 64 + b) * 2560;
    for (int e = threadIdx.x; e < 512; e += 256) dst[e] = f2b(src[e]);
}

// packed gate weights: rows 0..2047 r/z (K=2560 = Wih|Whh); 2048..3071 i_n (K=1536);
// 3072..4095 h_n (K=1024)
__global__ __launch_bounds__(256) void k_prepw(const float* __restrict__ Wih,
                                               const float* __restrict__ Whh,
                                               unsigned short* __restrict__ Wg) {
    int n = blockIdx.x, tid = threadIdx.x;
    int cl = n >> 10;
    if (cl < 2) {
        long base = (long)n * 2560;
        const float* wi = Wih + (long)n * 1536;
        const float* wh = Whh + (long)n * 1024;
        for (int k = tid; k < 1536; k += 256) Wg[base + k] = f2b(wi[k]);
        for (int k = tid; k < 1024; k += 256) Wg[base + 1536 + k] = f2b(wh[k]);
    } else if (cl == 2) {
        long base = 5242880L + (long)(n - 2048) * 1536;
        const float* wi = Wih + (long)n * 1536;
        for (int k = tid; k < 1536; k += 256) Wg[base + k] = f2b(wi[k]);
    } else {
        long base = 6815744L + (long)(n - 3072) * 1024;
        const float* wh = Whh + (long)(n - 1024) * 1024;
        for (int k = tid; k < 1024; k += 256) Wg[base + k] = f2b(wh[k]);
    }
}

// ---------------- ctx_proj GEMM: BM=64 x BN=512, BK=64, dbuf swizzled LDS ------
__global__ __launch_bounds__(512) void k_gemm(const float* __restrict__ A,
                                              const unsigned short* __restrict__ Bt,
                                              unsigned short* __restrict__ Cb) {
    __shared__ short As[2][4096];
    int tid = threadIdx.x, lane = tid & 63, w = tid >> 6;
    int bm = blockIdx.x % 196, bn = blockIdx.x / 196;
    long m0 = (long)bm * 64;
    int wn0 = bn * 512 + w * 64;
    int mr = lane & 15, kb = lane >> 4;
    int row = tid >> 3, grp = tid & 7;
    int wq = grp ^ (row & 7);
    const float* asrc = A + (m0 + row) * 1024 + grp * 8;

    f32x4 acc[4][4];
#pragma unroll
    for (int i = 0; i < 4; i++)
#pragma unroll
        for (int j = 0; j < 4; j++) acc[i][j] = zero4();

    float4 a0 = *(const float4*)(asrc);
    float4 a1 = *(const float4*)(asrc + 4);
    int buf = 0;
    for (int kt = 0; kt < 16; ++kt) {
        s16x8 pk = { (short)f2b(a0.x), (short)f2b(a0.y), (short)f2b(a0.z), (short)f2b(a0.w),
                     (short)f2b(a1.x), (short)f2b(a1.y), (short)f2b(a1.z), (short)f2b(a1.w) };
        *(s16x8*)&As[buf][row * 64 + wq * 8] = pk;
        __syncthreads();
        if (kt < 15) {
            a0 = *(const float4*)(asrc + (kt + 1) * 64);
            a1 = *(const float4*)(asrc + (kt + 1) * 64 + 4);
        }
#pragma unroll
        for (int ks = 0; ks < 2; ++ks) {
            int xg = ((ks * 4 + kb) ^ (mr & 7)) * 8;
            s16x8 af[4], bfr[4];
#pragma unroll
            for (int mt = 0; mt < 4; ++mt)
                af[mt] = *(s16x8*)&As[buf][(mt * 16 + mr) * 64 + xg];
#pragma unroll
            for (int nt = 0; nt < 4; ++nt)
                bfr[nt] = *(const s16x8*)(Bt + (long)(wn0 + nt * 16 + mr) * 1024 +
                                          kt * 64 + ks * 32 + kb * 8);
#pragma unroll
            for (int mt = 0; mt < 4; ++mt)
#pragma unroll
                for (int nt = 0; nt < 4; ++nt)
                    acc[mt][nt] = MFMA(af[mt], bfr[nt], acc[mt][nt]);
        }
        buf ^= 1;
    }
#pragma unroll
    for (int mt = 0; mt < 4; ++mt)
#pragma unroll
        for (int nt = 0; nt < 4; ++nt)
#pragma unroll
            for (int j = 0; j < 4; ++j)
                Cb[(m0 + mt * 16 + kb * 4 + j) * 1024 + wn0 + nt * 16 + mr] =
                    f2b(acc[mt][nt][j]);
}

// ---------------- mega-kernel helpers ----------------
__device__ __forceinline__ void tail_hg(int gw, int lane, int tn,
                                        const unsigned short* hbf,
                                        const unsigned short* attbf,
                                        const unsigned short* Wg,
                                        const unsigned short* xc,
                                        float* hpp, float* gp1) {
    int mr = lane & 15, kb = lane >> 4;
    if (gw < 256) {
        int vt = gw >> 2, mq = gw & 3;
        int vn0 = vt * 16, m0 = mq * 16;
        const unsigned short* ap = hbf + (long)(m0 + mr) * 1024 + kb * 8;
        const unsigned short* bp = attbf + (long)(vn0 + mr) * 1024 + kb * 8;
        f32x4 acc = wg16(ap, bp, 1024, zero4());
#pragma unroll
        for (int j = 0; j < 4; ++j)
            hpp[(long)(m0 + kb * 4 + j) * 1024 + vn0 + mr] = acc[j];
    } else if (gw < 1280) {
        int g = gw - 256, vt = g >> 2, mq = g & 3;
        int vn0 = vt * 16, m0 = mq * 16, cl = vn0 >> 10, vn = vn0 + mr;
        const unsigned short* xr = xc + (long)tn * 163840 + (long)(m0 + mr) * 2560;
        f32x4 acc = zero4();
        if (cl < 2) {
            const unsigned short* bp = Wg + (long)vn * 2560;
            acc = wg16(xr + kb * 8, bp + kb * 8, 512, acc);
            acc = wg16(xr + 1536 + kb * 8, bp + 1536 + kb * 8, 1024, acc);
        } else if (cl == 2) {
            const unsigned short* bp = Wg + 5242880L + (long)(vn - 2048) * 1536;
            acc = wg16(xr + kb * 8, bp + kb * 8, 512, acc);
        } else {
            const unsigned short* bp = Wg + 6815744L + (long)(vn - 3072) * 1024;
            acc = wg16(xr + 1536 + kb * 8, bp + kb * 8, 1024, acc);
        }
#pragma unroll
        for (int j = 0; j < 4; ++j)
            gp1[(long)(m0 + kb * 4 + j) * 4096 + vn] = acc[j];
    }
}

__device__ __forceinline__ void do_lse(int b, int tt, const float* pm, const float* ps,
                                       const unsigned short* obf, const float* o2pW,
                                       const float* o2pb, const int* y, float* out,
                                       int lane) {
    int tgt = y[(tt + 1) * 64 + b];
    float m = -1e30f, s = 0.f;
    for (int i = lane; i < 2000; i += 64) {
        float mi = pm[(long)i * 64 + b], si = ps[(long)i * 64 + b];
        float nm = fmaxf(m, mi);
        s = s * __expf(m - nm) + si * __expf(mi - nm);
        m = nm;
    }
#pragma unroll
    for (int off = 32; off; off >>= 1) {
        float mo = __shfl_xor(m, off, 64), so = __shfl_xor(s, off, 64);
        float nm = fmaxf(m, mo);
        s = s * __expf(m - nm) + so * __expf(mo - nm);
        m = nm;
    }
    float d = 0.f;
    const float* wr = o2pW + (long)tgt * 512;
#pragma unroll
    for (int r = 0; r < 8; ++r)
        d += b2f(obf[(long)b * 512 + lane + r * 64]) * wr[lane + r * 64];
#pragma unroll
    for (int off = 32; off; off >>= 1) d += __shfl_xor(d, off, 64);
    if (lane == 0 && tgt != 0)
        atomicAdd(out, (m + __logf(s)) - (d + o2pb[tgt]));
}

// ---------------- the persistent decoder kernel ----------------
__global__ __launch_bounds__(512) void k_mega(
    const float* __restrict__ ctx, const int* __restrict__ y,
    const float* __restrict__ mlp, const float* __restrict__ bih,
    const float* __restrict__ bhh, const float* __restrict__ h2ob,
    const float* __restrict__ octxb, const float* __restrict__ o2pW,
    const float* __restrict__ o2pb,
    const unsigned short* __restrict__ cpbf, const unsigned short* __restrict__ attbf,
    const unsigned short* __restrict__ Wg, const unsigned short* __restrict__ h2obf,
    const unsigned short* __restrict__ octxbf, const unsigned short* __restrict__ o2pbf,
    unsigned short* __restrict__ xc, unsigned short* __restrict__ hbf,
    unsigned short* __restrict__ obf,
    float* __restrict__ hf32, float* __restrict__ hpp,
    float* __restrict__ gp1, float* __restrict__ gp2,
    float* __restrict__ a2f, float* __restrict__ scb,
    float* __restrict__ pm, float* __restrict__ ps,
    float* out, unsigned* barcnt) {
    const int tid = threadIdx.x, lane = tid & 63, wv = tid >> 6;
    const int gw = blockIdx.x * 8 + wv;
    const int mr = lane & 15, kb = lane >> 4;
    unsigned rnd = 0;

    // mlp fragment for scores (lane -> cols lane*16..lane*16+15)
    f32x4 ml0 = *(const f32x4*)(mlp + lane * 16);
    f32x4 ml1 = *(const f32x4*)(mlp + lane * 16 + 4);
    f32x4 ml2 = *(const f32x4*)(mlp + lane * 16 + 8);
    f32x4 ml3 = *(const f32x4*)(mlp + lane * 16 + 12);

    // Ph0: hproj(0) (h=0) + gates1(0)
    tail_hg(gw, lane, 0, hbf, attbf, Wg, xc, hpp, gp1);
    gbar(barcnt, (++rnd) * NBLK);

    for (int t = 0; t < TS_; ++t) {
        // ---- PhA: scores(t)  ||  lse(t-1) ----
        if (gw < 1984) {
            for (int p = gw; p < 12544; p += 1984) {
                int b = p & 63;
                const unsigned short* cp = cpbf + (long)p * 1024 + lane * 16;
                s16x8 c0 = *(const s16x8*)cp;
                s16x8 c1 = *(const s16x8*)(cp + 8);
                const f32x4* hv = (const f32x4*)(hpp + (long)b * 1024 + lane * 16);
                f32x4 h0 = hv[0], h1 = hv[1], h2 = hv[2], h3 = hv[3];
                float acc = 0.f;
#pragma unroll
                for (int j = 0; j < 4; ++j)
                    acc += fast_tanh(b2f((unsigned short)c0[j]) + h0[j]) * ml0[j];
#pragma unroll
                for (int j = 0; j < 4; ++j)
                    acc += fast_tanh(b2f((unsigned short)c0[j + 4]) + h1[j]) * ml1[j];
#pragma unroll
                for (int j = 0; j < 4; ++j)
                    acc += fast_tanh(b2f((unsigned short)c1[j]) + h2[j]) * ml2[j];
#pragma unroll
                for (int j = 0; j < 4; ++j)
                    acc += fast_tanh(b2f((unsigned short)c1[j + 4]) + h3[j]) * ml3[j];
#pragma unroll
                for (int off = 32; off; off >>= 1) acc += __shfl_xor(acc, off, 64);
                if (lane == 0) scb[b * 196 + (p >> 6)] = acc;
            }
        } else if (t > 0) {
            do_lse(gw - 1984, t - 1, pm, ps, obf, o2pW, o2pb, y, out, lane);
        }
        gbar(barcnt, (++rnd) * NBLK);

        // ---- PhB: softmax + z -> xc z-slot ----
        if (gw < 1024) {
            int b = gw >> 4, ch = gw & 15;
            const float* sc = scb + b * 196;
            float v0 = sc[lane], v1 = sc[lane + 64], v2 = sc[lane + 128];
            float v3 = (lane < 4) ? sc[192 + lane] : -1e30f;
            float m = fmaxf(fmaxf(v0, v1), fmaxf(v2, v3));
#pragma unroll
            for (int off = 32; off; off >>= 1) m = fmaxf(m, __shfl_xor(m, off, 64));
            float pI = __expf(v0 - m) + __expf(v1 - m) + __expf(v2 - m);
            if (lane < 4) pI += __expf(v3 - m);
#pragma unroll
            for (int off = 32; off; off >>= 1) pI += __shfl_xor(pI, off, 64);
            float inv = 1.f / pI;
            int c0i = ch * 64 + (lane & 31) * 2;
            int sbeg = (lane >> 5) * 98;
            const float* basep = ctx + (long)b * 1024 + c0i;
            float a0 = 0.f, a1 = 0.f;
            for (int s = sbeg; s < sbeg + 98; s += 2) {
                float al0 = __expf(sc[s] - m) * inv;
                float al1 = __expf(sc[s + 1] - m) * inv;
                float2 v0v = *(const float2*)(basep + (long)s * 65536);
                float2 v1v = *(const float2*)(basep + (long)(s + 1) * 65536);
                a0 += al0 * v0v.x + al1 * v1v.x;
                a1 += al0 * v0v.y + al1 * v1v.y;
            }
            a0 += __shfl_xor(a0, 32, 64);
            a1 += __shfl_xor(a1, 32, 64);
            if (lane < 32) {
                ushort2 o = { f2b(a0), f2b(a1) };
                *(ushort2*)(xc + (long)(t * 64 + b) * 2560 + 512 + c0i) = o;
            }
        }
        gbar(barcnt, (++rnd) * NBLK);

        // ---- PhC: gates2 (z-part) + out_a2 ----
        {
            const unsigned short* xzt = xc + (long)t * 163840;
            if (gw < 768) {
                int vn0, mq = gw & 3;
                const unsigned short* bp;
                if (gw < 512) {
                    vn0 = (gw >> 2) * 16;
                    bp = Wg + (long)(vn0 + mr) * 2560 + 512;
                } else {
                    vn0 = 2048 + ((gw - 512) >> 2) * 16;
                    bp = Wg + 5242880L + (long)(vn0 + mr - 2048) * 1536 + 512;
                }
                int m0 = mq * 16;
                const unsigned short* ap = xzt + (long)(m0 + mr) * 2560 + 512 + kb * 8;
                f32x4 acc = wg16(ap, bp + kb * 8, 1024, zero4());
#pragma unroll
                for (int j = 0; j < 4; ++j)
                    gp2[(long)(m0 + kb * 4 + j) * 4096 + vn0 + mr] = acc[j];
            } else if (gw < 896) {
                int uu = gw - 768;
                int n0 = (uu >> 2) * 16, m0 = (uu & 3) * 16, e = n0 + mr;
                const unsigned short* ap = xzt + (long)(m0 + mr) * 2560 + 512 + kb * 8;
                const unsigned short* bp = octxbf + (long)e * 1024 + kb * 8;
                f32x4 acc = wg16(ap, bp, 1024, zero4());
                float ob = octxb[e];
#pragma unroll
                for (int j = 0; j < 4; ++j) {
                    int bb = m0 + kb * 4 + j;
                    a2f[(long)bb * 512 + e] = acc[j] + ob + b2f(xzt[(long)bb * 2560 + e]);
                }
            }
        }
        gbar(barcnt, (++rnd) * NBLK);

        // ---- PhD: GRU finish ----
        {
            int idx = blockIdx.x * 512 + tid;
            if (idx < 65536) {
                int b = idx >> 10, j = idx & 1023;
                const float* g1 = gp1 + (long)b * 4096;
                const float* g2 = gp2 + (long)b * 4096;
                float r  = sigmoidf_(g1[j] + g2[j] + bih[j] + bhh[j]);
                float zz = sigmoidf_(g1[1024 + j] + g2[1024 + j] + bih[1024 + j] + bhh[1024 + j]);
                float n  = fast_tanh(g1[2048 + j] + g2[2048 + j] + bih[2048 + j] +
                                     r * (g1[3072 + j] + bhh[2048 + j]));
                float h = (1.f - zz) * n + zz * hf32[idx];
                hf32[idx] = h;
                unsigned short hb = f2b(h);
                hbf[idx] = hb;
                if (t < TS_ - 1)
                    xc[(long)(t + 1) * 163840 + (long)b * 2560 + 1536 + j] = hb;
            }
        }
        gbar(barcnt, (++rnd) * NBLK);

        // ---- PhE: output head a1 + finish ----
        if (gw < 128) {
            int n0 = (gw >> 2) * 16, m0 = (gw & 3) * 16, e = n0 + mr;
            const unsigned short* ap = hbf + (long)(m0 + mr) * 1024 + kb * 8;
            const unsigned short* bp = h2obf + (long)e * 1024 + kb * 8;
            f32x4 acc = wg16(ap, bp, 1024, zero4());
            float b1 = h2ob[e];
#pragma unroll
            for (int j = 0; j < 4; ++j) {
                int bb = m0 + kb * 4 + j;
                float val = fast_tanh(fast_tanh(acc[j] + b1) + a2f[(long)bb * 512 + e]);
                obf[(long)bb * 512 + e] = f2b(val);
            }
        }
        gbar(barcnt, (++rnd) * NBLK);

        // ---- PhF: vocab(t)  ||  hproj(t+1) + gates1(t+1) ----
        for (int vu = gw; vu < 8000; vu += 2048) {
            int vt = vu >> 2, mq = vu & 3;
            int v0 = vt * 16, m0 = mq * 16;
            const unsigned short* ap = obf + (long)(m0 + mr) * 512 + kb * 8;
            const unsigned short* bp = o2pbf + (long)(v0 + mr) * 512 + kb * 8;
            f32x4 acc = wg16(ap, bp, 512, zero4());
            float bv = o2pb[v0 + mr];
#pragma unroll
            for (int j = 0; j < 4; ++j) {
                float x = acc[j] + bv;
                float mm = x;
                mm = fmaxf(mm, __shfl_xor(mm, 1, 64));
                mm = fmaxf(mm, __shfl_xor(mm, 2, 64));
                mm = fmaxf(mm, __shfl_xor(mm, 4, 64));
                mm = fmaxf(mm, __shfl_xor(mm, 8, 64));
                float ee = __expf(x - mm);
                ee += __shfl_xor(ee, 1, 64);
                ee += __shfl_xor(ee, 2, 64);
                ee += __shfl_xor(ee, 4, 64);
                ee += __shfl_xor(ee, 8, 64);
                if (mr == 0) {
                    int bb = m0 + kb * 4 + j;
                    pm[(long)vt * 64 + bb] = mm;
                    ps[(long)vt * 64 + bb] = ee;
                }
            }
        }
        if (t < TS_ - 1)
            tail_hg(gw, lane, t + 1, hbf, attbf, Wg, xc, hpp, gp1);
        gbar(barcnt, (++rnd) * NBLK);
    }

    // epilogue: lse for final step
    if (gw >= 1984)
        do_lse(gw - 1984, TS_ - 1, pm, ps, obf, o2pW, o2pb, y, out, lane);
}

extern "C" void kernel_launch(void* const* d_in, const int* in_sizes, int n_in,
                              void* d_out, int out_size, void* d_ws, size_t ws_size,
                              hipStream_t stream) {
    const float* ctx     = (const float*)d_in[0];
    const int*   y       = (const int*)d_in[1];
    const float* embW    = (const float*)d_in[2];
    const float* att_c2c = (const float*)d_in[3];
    const float* att_h2c = (const float*)d_in[4];
    const float* mlp     = (const float*)d_in[5];
    const float* Wih     = (const float*)d_in[6];
    const float* bih     = (const float*)d_in[7];
    const float* Whh     = (const float*)d_in[8];
    const float* bhh     = (const float*)d_in[9];
    const float* h2oW    = (const float*)d_in[10];
    const float* h2ob    = (const float*)d_in[11];
    const float* octxW   = (const float*)d_in[12];
    const float* octxb   = (const float*)d_in[13];
    const float* o2pW    = (const float*)d_in[14];
    const float* o2pb    = (const float*)d_in[15];
    float* out = (float*)d_out;

    char* base = (char*)d_ws;
    unsigned short* cpbf   = (unsigned short*)base; base += 25690112L;  // [12544][1024]
    unsigned short* c2cT   = (unsigned short*)base; base += 2097152L;   // [n][k]
    unsigned short* attbf  = (unsigned short*)base; base += 2097152L;   // [c][h]
    unsigned short* Wg     = (unsigned short*)base; base += 15728640L;  // packed gates
    unsigned short* h2obf  = (unsigned short*)base; base += 1048576L;
    unsigned short* octxbf = (unsigned short*)base; base += 1048576L;
    unsigned short* o2pbf  = (unsigned short*)base; base += 32768000L;
    unsigned short* xc     = (unsigned short*)base; base += 6225920L;   // [19][64][2560]
    unsigned short* hbf    = (unsigned short*)base; base += 131072L;    // [64][1024]
    unsigned short* obf    = (unsigned short*)base; base += 65536L;     // [64][512]
    float* hf32   = (float*)base; base += 262144L;                      // [64][1024]
    float* hpp    = (float*)base; base += 262144L;                      // [64][1024]
    float* gp1    = (float*)base; base += 1048576L;                     // [64][4096]
    float* gp2    = (float*)base; base += 1048576L;                     // [64][4096]
    float* a2f    = (float*)base; base += 131072L;                      // [64][512]
    float* scb    = (float*)base; base += 50176L;                       // [64][196]
    float* pm     = (float*)base; base += 512000L;                      // [2000][64]
    float* ps     = (float*)base; base += 512000L;
    unsigned* barcnt = (unsigned*)base; base += 256L;

    hipMemsetAsync(d_out, 0, sizeof(float), stream);
    hipMemsetAsync(hf32, 0, 262144, stream);
    hipMemsetAsync(hbf, 0, 131072, stream);
    hipMemsetAsync(xc, 0, 6225920, stream);
    hipMemsetAsync(barcnt, 0, 256, stream);

    // prep
    k_yemb<<<TS_ * 64, 256, 0, stream>>>(y, embW, xc);
    k_tcvt<<<dim3(32, 32), dim3(32, 8), 0, stream>>>(att_c2c, c2cT);
    k_tcvt<<<dim3(32, 32), dim3(32, 8), 0, stream>>>(att_h2c, attbf);
    k_cvt<<<512, 256, 0, stream>>>(h2oW, h2obf, 524288L);
    k_cvt<<<512, 256, 0, stream>>>(octxW, octxbf, 524288L);
    k_cvt<<<2048, 256, 0, stream>>>(o2pW, o2pbf, 16384000L);
    k_prepw<<<4096, 256, 0, stream>>>(Wih, Whh, Wg);
    k_gemm<<<392, 512, 0, stream>>>(ctx, c2cT, cpbf);

    // the whole 19-step decoder in one persistent kernel
    k_mega<<<NBLK, NTHR, 0, stream>>>(
        ctx, y, mlp, bih, bhh, h2ob, octxb, o2pW, o2pb,
        cpbf, attbf, Wg, h2obf, octxbf, o2pbf,
        xc, hbf, obf, hf32, hpp, gp1, gp2, a2f, scb, pm, ps,
        out, barcnt);
}

// Round 5
// 13528.441 us; speedup vs baseline: 1.0691x; 1.0691x over previous
//
#include <hip/hip_runtime.h>
#include <math.h>

#define TS_ 19   // T-1 decode steps
#define NBLK 256
#define NTHR 512

typedef float f32x4 __attribute__((ext_vector_type(4)));
typedef short s16x8 __attribute__((ext_vector_type(8)));

__device__ __forceinline__ float sigmoidf_(float x) { return 1.f / (1.f + __expf(-x)); }

__device__ __forceinline__ float fast_tanh(float x) {
    float ax = fabsf(x);
    float e = __expf(-2.f * ax);
    float r = (1.f - e) * __builtin_amdgcn_rcpf(1.f + e);
    return copysignf(r, x);
}

__device__ __forceinline__ unsigned short f2b(float x) {
    union { float f; unsigned u; } v; v.f = x;
    unsigned r = v.u + 0x7fffu + ((v.u >> 16) & 1u);
    return (unsigned short)(r >> 16);
}
__device__ __forceinline__ float b2f(unsigned short u) {
    union { unsigned u; float f; } v; v.u = ((unsigned)u) << 16; return v.f;
}

#define MFMA(a, b, c) __builtin_amdgcn_mfma_f32_16x16x32_bf16((a), (b), (c), 0, 0, 0)

__device__ __forceinline__ f32x4 zero4() { return (f32x4){0.f, 0.f, 0.f, 0.f}; }

__device__ __forceinline__ f32x4 wg16(const unsigned short* ap, const unsigned short* bp,
                                      int nk, f32x4 acc) {
#pragma unroll 4
    for (int k = 0; k < nk; k += 32)
        acc = MFMA(*(const s16x8*)(ap + k), *(const s16x8*)(bp + k), acc);
    return acc;
}

// ---------------- device-wide barrier: arrive counter + release flag ----------
// arrive: only written (fetch_add), never polled -> no line bouncing.
// release: single writer per round, 255 read-only pollers.
__device__ __forceinline__ void gbar(unsigned* arrive, unsigned* release, unsigned r) {
    __threadfence();
    __syncthreads();
    if (threadIdx.x == 0) {
        unsigned prev = __hip_atomic_fetch_add(arrive, 1u, __ATOMIC_ACQ_REL,
                                               __HIP_MEMORY_SCOPE_AGENT);
        if (prev == r * NBLK - 1) {
            __hip_atomic_store(release, r, __ATOMIC_RELEASE, __HIP_MEMORY_SCOPE_AGENT);
        } else {
            while (__hip_atomic_load(release, __ATOMIC_ACQUIRE,
                                     __HIP_MEMORY_SCOPE_AGENT) < r)
                __builtin_amdgcn_s_sleep(4);
        }
    }
    __syncthreads();
    __threadfence();
}

// ---------------- prep kernels ----------------
__global__ __launch_bounds__(256) void k_cvt(const float* __restrict__ in,
                                             unsigned short* __restrict__ out, long n) {
    long i = ((long)blockIdx.x * 256 + threadIdx.x) * 4;
    long stride = (long)gridDim.x * 1024;
    for (; i < n; i += stride) {
        float4 v = *(const float4*)(in + i);
        ushort4 o = { f2b(v.x), f2b(v.y), f2b(v.z), f2b(v.w) };
        *(ushort4*)(out + i) = o;
    }
}

__global__ void k_tcvt(const float* __restrict__ in, unsigned short* __restrict__ out) {
    __shared__ float tile[32][33];
    int bx = blockIdx.x * 32, by = blockIdx.y * 32;
    int x = threadIdx.x, y0 = threadIdx.y;
    for (int yy = y0; yy < 32; yy += 8) tile[yy][x] = in[(by + yy) * 1024 + bx + x];
    __syncthreads();
    for (int yy = y0; yy < 32; yy += 8) out[(bx + yy) * 1024 + by + x] = f2b(tile[x][yy]);
}

__global__ __launch_bounds__(256) void k_yemb(const int* __restrict__ y,
                                              const float* __restrict__ embW,
                                              unsigned short* __restrict__ xc) {
    int t = blockIdx.x >> 6, b = blockIdx.x & 63;
    int row = y[t * 64 + b];
    const float* src = embW + (long)row * 512;
    unsigned short* dst = xc + (long)(t * 64 + b) * 2560;
    for (int e = threadIdx.x; e < 512; e += 256) dst[e] = f2b(src[e]);
}

// packed gate weights: rows 0..2047 r/z (K=2560 = Wih|Whh); 2048..3071 i_n (K=1536);
// 3072..4095 h_n (K=1024)
__global__ __launch_bounds__(256) void k_prepw(const float* __restrict__ Wih,
                                               const float* __restrict__ Whh,
                                               unsigned short* __restrict__ Wg) {
    int n = blockIdx.x, tid = threadIdx.x;
    int cl = n >> 10;
    if (cl < 2) {
        long base = (long)n * 2560;
        const float* wi = Wih + (long)n * 1536;
        const float* wh = Whh + (long)n * 1024;
        for (int k = tid; k < 1536; k += 256) Wg[base + k] = f2b(wi[k]);
        for (int k = tid; k < 1024; k += 256) Wg[base + 1536 + k] = f2b(wh[k]);
    } else if (cl == 2) {
        long base = 5242880L + (long)(n - 2048) * 1536;
        const float* wi = Wih + (long)n * 1536;
        for (int k = tid; k < 1536; k += 256) Wg[base + k] = f2b(wi[k]);
    } else {
        long base = 6815744L + (long)(n - 3072) * 1024;
        const float* wh = Whh + (long)(n - 1024) * 1024;
        for (int k = tid; k < 1024; k += 256) Wg[base + k] = f2b(wh[k]);
    }
}

// ---------------- ctx_proj GEMM: BM=64 x BN=512, BK=64, dbuf swizzled LDS ------
__global__ __launch_bounds__(512) void k_gemm(const float* __restrict__ A,
                                              const unsigned short* __restrict__ Bt,
                                              unsigned short* __restrict__ Cb) {
    __shared__ short As[2][4096];
    int tid = threadIdx.x, lane = tid & 63, w = tid >> 6;
    int bm = blockIdx.x % 196, bn = blockIdx.x / 196;
    long m0 = (long)bm * 64;
    int wn0 = bn * 512 + w * 64;
    int mr = lane & 15, kb = lane >> 4;
    int row = tid >> 3, grp = tid & 7;
    int wq = grp ^ (row & 7);
    const float* asrc = A + (m0 + row) * 1024 + grp * 8;

    f32x4 acc[4][4];
#pragma unroll
    for (int i = 0; i < 4; i++)
#pragma unroll
        for (int j = 0; j < 4; j++) acc[i][j] = zero4();

    float4 a0 = *(const float4*)(asrc);
    float4 a1 = *(const float4*)(asrc + 4);
    int buf = 0;
    for (int kt = 0; kt < 16; ++kt) {
        s16x8 pk = { (short)f2b(a0.x), (short)f2b(a0.y), (short)f2b(a0.z), (short)f2b(a0.w),
                     (short)f2b(a1.x), (short)f2b(a1.y), (short)f2b(a1.z), (short)f2b(a1.w) };
        *(s16x8*)&As[buf][row * 64 + wq * 8] = pk;
        __syncthreads();
        if (kt < 15) {
            a0 = *(const float4*)(asrc + (kt + 1) * 64);
            a1 = *(const float4*)(asrc + (kt + 1) * 64 + 4);
        }
#pragma unroll
        for (int ks = 0; ks < 2; ++ks) {
            int xg = ((ks * 4 + kb) ^ (mr & 7)) * 8;
            s16x8 af[4], bfr[4];
#pragma unroll
            for (int mt = 0; mt < 4; ++mt)
                af[mt] = *(s16x8*)&As[buf][(mt * 16 + mr) * 64 + xg];
#pragma unroll
            for (int nt = 0; nt < 4; ++nt)
                bfr[nt] = *(const s16x8*)(Bt + (long)(wn0 + nt * 16 + mr) * 1024 +
                                          kt * 64 + ks * 32 + kb * 8);
#pragma unroll
            for (int mt = 0; mt < 4; ++mt)
#pragma unroll
                for (int nt = 0; nt < 4; ++nt)
                    acc[mt][nt] = MFMA(af[mt], bfr[nt], acc[mt][nt]);
        }
        buf ^= 1;
    }
#pragma unroll
    for (int mt = 0; mt < 4; ++mt)
#pragma unroll
        for (int nt = 0; nt < 4; ++nt)
#pragma unroll
            for (int j = 0; j < 4; ++j)
                Cb[(m0 + mt * 16 + kb * 4 + j) * 1024 + wn0 + nt * 16 + mr] =
                    f2b(acc[mt][nt][j]);
}

// ---------------- mega-kernel helpers ----------------
__device__ __forceinline__ void tail_hg(int gw, int lane, int tn,
                                        const unsigned short* hbf,
                                        const unsigned short* attbf,
                                        const unsigned short* Wg,
                                        const unsigned short* xc,
                                        float* hpp, float* gp1) {
    int mr = lane & 15, kb = lane >> 4;
    if (gw < 256) {
        int vt = gw >> 2, mq = gw & 3;
        int vn0 = vt * 16, m0 = mq * 16;
        const unsigned short* ap = hbf + (long)(m0 + mr) * 1024 + kb * 8;
        const unsigned short* bp = attbf + (long)(vn0 + mr) * 1024 + kb * 8;
        f32x4 acc = wg16(ap, bp, 1024, zero4());
#pragma unroll
        for (int j = 0; j < 4; ++j)
            hpp[(long)(m0 + kb * 4 + j) * 1024 + vn0 + mr] = acc[j];
    } else if (gw < 1280) {
        int g = gw - 256, vt = g >> 2, mq = g & 3;
        int vn0 = vt * 16, m0 = mq * 16, cl = vn0 >> 10, vn = vn0 + mr;
        const unsigned short* xr = xc + (long)tn * 163840 + (long)(m0 + mr) * 2560;
        f32x4 acc = zero4();
        if (cl < 2) {
            const unsigned short* bp = Wg + (long)vn * 2560;
            acc = wg16(xr + kb * 8, bp + kb * 8, 512, acc);
            acc = wg16(xr + 1536 + kb * 8, bp + 1536 + kb * 8, 1024, acc);
        } else if (cl == 2) {
            const unsigned short* bp = Wg + 5242880L + (long)(vn - 2048) * 1536;
            acc = wg16(xr + kb * 8, bp + kb * 8, 512, acc);
        } else {
            const unsigned short* bp = Wg + 6815744L + (long)(vn - 3072) * 1024;
            acc = wg16(xr + 1536 + kb * 8, bp + kb * 8, 1024, acc);
        }
#pragma unroll
        for (int j = 0; j < 4; ++j)
            gp1[(long)(m0 + kb * 4 + j) * 4096 + vn] = acc[j];
    }
}

__device__ __forceinline__ void do_lse(int b, int tt, const float* pm, const float* ps,
                                       const unsigned short* obf, const float* o2pW,
                                       const float* o2pb, const int* y, float* out,
                                       int lane) {
    int tgt = y[(tt + 1) * 64 + b];
    float m = -1e30f, s = 0.f;
    for (int i = lane; i < 2000; i += 64) {
        float mi = pm[(long)i * 64 + b], si = ps[(long)i * 64 + b];
        float nm = fmaxf(m, mi);
        s = s * __expf(m - nm) + si * __expf(mi - nm);
        m = nm;
    }
#pragma unroll
    for (int off = 32; off; off >>= 1) {
        float mo = __shfl_xor(m, off, 64), so = __shfl_xor(s, off, 64);
        float nm = fmaxf(m, mo);
        s = s * __expf(m - nm) + so * __expf(mo - nm);
        m = nm;
    }
    float d = 0.f;
    const float* wr = o2pW + (long)tgt * 512;
#pragma unroll
    for (int r = 0; r < 8; ++r)
        d += b2f(obf[(long)b * 512 + lane + r * 64]) * wr[lane + r * 64];
#pragma unroll
    for (int off = 32; off; off >>= 1) d += __shfl_xor(d, off, 64);
    if (lane == 0 && tgt != 0)
        atomicAdd(out, (m + __logf(s)) - (d + o2pb[tgt]));
}

// ---------------- the persistent decoder kernel ----------------
__global__ __launch_bounds__(512) void k_mega(
    const int* __restrict__ y,
    const float* __restrict__ mlp, const float* __restrict__ bih,
    const float* __restrict__ bhh, const float* __restrict__ h2ob,
    const float* __restrict__ octxb, const float* __restrict__ o2pW,
    const float* __restrict__ o2pb,
    const unsigned short* __restrict__ ctxbf,
    const unsigned short* __restrict__ cpbf, const unsigned short* __restrict__ attbf,
    const unsigned short* __restrict__ Wg, const unsigned short* __restrict__ h2obf,
    const unsigned short* __restrict__ octxbf, const unsigned short* __restrict__ o2pbf,
    unsigned short* __restrict__ xc, unsigned short* __restrict__ hbf,
    unsigned short* __restrict__ obf,
    float* __restrict__ hf32, float* __restrict__ hpp,
    float* __restrict__ gp1, float* __restrict__ gp2,
    float* __restrict__ a2f, float* __restrict__ scb,
    float* __restrict__ pm, float* __restrict__ ps,
    float* out, unsigned* barcnt) {
    const int tid = threadIdx.x, lane = tid & 63, wv = tid >> 6;
    const int gw = blockIdx.x * 8 + wv;
    const int mr = lane & 15, kb = lane >> 4;
    unsigned* arrive = barcnt;
    unsigned* release = barcnt + 32;   // separate cacheline
    unsigned rnd = 0;

    // mlp fragment for scores (lane -> cols lane*16..lane*16+15)
    f32x4 ml0 = *(const f32x4*)(mlp + lane * 16);
    f32x4 ml1 = *(const f32x4*)(mlp + lane * 16 + 4);
    f32x4 ml2 = *(const f32x4*)(mlp + lane * 16 + 8);
    f32x4 ml3 = *(const f32x4*)(mlp + lane * 16 + 12);

    // Ph0: hproj(0) (h=0) + gates1(0)
    tail_hg(gw, lane, 0, hbf, attbf, Wg, xc, hpp, gp1);
    gbar(arrive, release, ++rnd);

    for (int t = 0; t < TS_; ++t) {
        // ---- PhA: scores(t)  ||  lse(t-1) ----
        if (gw < 1984) {
            for (int p = gw; p < 12544; p += 1984) {
                int b = p & 63;
                const unsigned short* cp = cpbf + (long)p * 1024 + lane * 16;
                s16x8 c0 = *(const s16x8*)cp;
                s16x8 c1 = *(const s16x8*)(cp + 8);
                const f32x4* hv = (const f32x4*)(hpp + (long)b * 1024 + lane * 16);
                f32x4 h0 = hv[0], h1 = hv[1], h2 = hv[2], h3 = hv[3];
                float acc = 0.f;
#pragma unroll
                for (int j = 0; j < 4; ++j)
                    acc += fast_tanh(b2f((unsigned short)c0[j]) + h0[j]) * ml0[j];
#pragma unroll
                for (int j = 0; j < 4; ++j)
                    acc += fast_tanh(b2f((unsigned short)c0[j + 4]) + h1[j]) * ml1[j];
#pragma unroll
                for (int j = 0; j < 4; ++j)
                    acc += fast_tanh(b2f((unsigned short)c1[j]) + h2[j]) * ml2[j];
#pragma unroll
                for (int j = 0; j < 4; ++j)
                    acc += fast_tanh(b2f((unsigned short)c1[j + 4]) + h3[j]) * ml3[j];
#pragma unroll
                for (int off = 32; off; off >>= 1) acc += __shfl_xor(acc, off, 64);
                if (lane == 0) scb[b * 196 + (p >> 6)] = acc;
            }
        } else if (t > 0) {
            do_lse(gw - 1984, t - 1, pm, ps, obf, o2pW, o2pb, y, out, lane);
        }
        gbar(arrive, release, ++rnd);

        // ---- PhB: softmax + z -> xc z-slot (reads ctxbf) ----
        if (gw < 2048) {
            int b = gw >> 5, ch = gw & 31;
            const float* sc = scb + b * 196;
            float v0 = sc[lane], v1 = sc[lane + 64], v2 = sc[lane + 128];
            float v3 = (lane < 4) ? sc[192 + lane] : -1e30f;
            float m = fmaxf(fmaxf(v0, v1), fmaxf(v2, v3));
#pragma unroll
            for (int off = 32; off; off >>= 1) m = fmaxf(m, __shfl_xor(m, off, 64));
            float pI = __expf(v0 - m) + __expf(v1 - m) + __expf(v2 - m);
            if (lane < 4) pI += __expf(v3 - m);
#pragma unroll
            for (int off = 32; off; off >>= 1) pI += __shfl_xor(pI, off, 64);
            float inv = 1.f / pI;
            int c0i = ch * 32 + (lane & 15) * 2;
            int sbeg = (lane >> 4) * 49;
            const unsigned short* basep = ctxbf + (long)b * 1024 + c0i;
            float a0 = 0.f, a1 = 0.f;
            for (int s = sbeg; s < sbeg + 49; ++s) {
                float al = __expf(sc[s] - m) * inv;
                unsigned v = *(const unsigned*)(basep + (long)s * 65536);
                a0 += al * b2f((unsigned short)(v & 0xffffu));
                a1 += al * b2f((unsigned short)(v >> 16));
            }
            a0 += __shfl_xor(a0, 16, 64); a0 += __shfl_xor(a0, 32, 64);
            a1 += __shfl_xor(a1, 16, 64); a1 += __shfl_xor(a1, 32, 64);
            if (lane < 16) {
                ushort2 o = { f2b(a0), f2b(a1) };
                *(ushort2*)(xc + (long)(t * 64 + b) * 2560 + 512 + c0i) = o;
            }
        }
        gbar(arrive, release, ++rnd);

        // ---- PhC: gates2 (z-part) + out_a2 ----
        {
            const unsigned short* xzt = xc + (long)t * 163840;
            if (gw < 768) {
                int vn0, mq = gw & 3;
                const unsigned short* bp;
                if (gw < 512) {
                    vn0 = (gw >> 2) * 16;
                    bp = Wg + (long)(vn0 + mr) * 2560 + 512;
                } else {
                    vn0 = 2048 + ((gw - 512) >> 2) * 16;
                    bp = Wg + 5242880L + (long)(vn0 + mr - 2048) * 1536 + 512;
                }
                int m0 = mq * 16;
                const unsigned short* ap = xzt + (long)(m0 + mr) * 2560 + 512 + kb * 8;
                f32x4 acc = wg16(ap, bp + kb * 8, 1024, zero4());
#pragma unroll
                for (int j = 0; j < 4; ++j)
                    gp2[(long)(m0 + kb * 4 + j) * 4096 + vn0 + mr] = acc[j];
            } else if (gw < 896) {
                int uu = gw - 768;
                int n0 = (uu >> 2) * 16, m0 = (uu & 3) * 16, e = n0 + mr;
                const unsigned short* ap = xzt + (long)(m0 + mr) * 2560 + 512 + kb * 8;
                const unsigned short* bp = octxbf + (long)e * 1024 + kb * 8;
                f32x4 acc = wg16(ap, bp, 1024, zero4());
                float ob = octxb[e];
#pragma unroll
                for (int j = 0; j < 4; ++j) {
                    int bb = m0 + kb * 4 + j;
                    a2f[(long)bb * 512 + e] = acc[j] + ob + b2f(xzt[(long)bb * 2560 + e]);
                }
            }
        }
        gbar(arrive, release, ++rnd);

        // ---- PhD: GRU finish ----
        {
            int idx = blockIdx.x * 512 + tid;
            if (idx < 65536) {
                int b = idx >> 10, j = idx & 1023;
                const float* g1 = gp1 + (long)b * 4096;
                const float* g2 = gp2 + (long)b * 4096;
                float r  = sigmoidf_(g1[j] + g2[j] + bih[j] + bhh[j]);
                float zz = sigmoidf_(g1[1024 + j] + g2[1024 + j] + bih[1024 + j] + bhh[1024 + j]);
                float n  = fast_tanh(g1[2048 + j] + g2[2048 + j] + bih[2048 + j] +
                                     r * (g1[3072 + j] + bhh[2048 + j]));
                float h = (1.f - zz) * n + zz * hf32[idx];
                hf32[idx] = h;
                unsigned short hb = f2b(h);
                hbf[idx] = hb;
                if (t < TS_ - 1)
                    xc[(long)(t + 1) * 163840 + (long)b * 2560 + 1536 + j] = hb;
            }
        }
        gbar(arrive, release, ++rnd);

        // ---- PhE: output head a1 + finish ----
        if (gw < 128) {
            int n0 = (gw >> 2) * 16, m0 = (gw & 3) * 16, e = n0 + mr;
            const unsigned short* ap = hbf + (long)(m0 + mr) * 1024 + kb * 8;
            const unsigned short* bp = h2obf + (long)e * 1024 + kb * 8;
            f32x4 acc = wg16(ap, bp, 1024, zero4());
            float b1 = h2ob[e];
#pragma unroll
            for (int j = 0; j < 4; ++j) {
                int bb = m0 + kb * 4 + j;
                float val = fast_tanh(fast_tanh(acc[j] + b1) + a2f[(long)bb * 512 + e]);
                obf[(long)bb * 512 + e] = f2b(val);
            }
        }
        gbar(arrive, release, ++rnd);

        // ---- PhF: vocab(t)  ||  hproj(t+1) + gates1(t+1) ----
        for (int vu = gw; vu < 8000; vu += 2048) {
            int vt = vu >> 2, mq = vu & 3;
            int v0 = vt * 16, m0 = mq * 16;
            const unsigned short* ap = obf + (long)(m0 + mr) * 512 + kb * 8;
            const unsigned short* bp = o2pbf + (long)(v0 + mr) * 512 + kb * 8;
            f32x4 acc = wg16(ap, bp, 512, zero4());
            float bv = o2pb[v0 + mr];
#pragma unroll
            for (int j = 0; j < 4; ++j) {
                float x = acc[j] + bv;
                float mm = x;
                mm = fmaxf(mm, __shfl_xor(mm, 1, 64));
                mm = fmaxf(mm, __shfl_xor(mm, 2, 64));
                mm = fmaxf(mm, __shfl_xor(mm, 4, 64));
                mm = fmaxf(mm, __shfl_xor(mm, 8, 64));
                float ee = __expf(x - mm);
                ee += __shfl_xor(ee, 1, 64);
                ee += __shfl_xor(ee, 2, 64);
                ee += __shfl_xor(ee, 4, 64);
                ee += __shfl_xor(ee, 8, 64);
                if (mr == 0) {
                    int bb = m0 + kb * 4 + j;
                    pm[(long)vt * 64 + bb] = mm;
                    ps[(long)vt * 64 + bb] = ee;
                }
            }
        }
        if (t < TS_ - 1)
            tail_hg(gw, lane, t + 1, hbf, attbf, Wg, xc, hpp, gp1);
        gbar(arrive, release, ++rnd);
    }

    // epilogue: lse for final step
    if (gw >= 1984)
        do_lse(gw - 1984, TS_ - 1, pm, ps, obf, o2pW, o2pb, y, out, lane);
}

extern "C" void kernel_launch(void* const* d_in, const int* in_sizes, int n_in,
                              void* d_out, int out_size, void* d_ws, size_t ws_size,
                              hipStream_t stream) {
    const float* ctx     = (const float*)d_in[0];
    const int*   y       = (const int*)d_in[1];
    const float* embW    = (const float*)d_in[2];
    const float* att_c2c = (const float*)d_in[3];
    const float* att_h2c = (const float*)d_in[4];
    const float* mlp     = (const float*)d_in[5];
    const float* Wih     = (const float*)d_in[6];
    const float* bih     = (const float*)d_in[7];
    const float* Whh     = (const float*)d_in[8];
    const float* bhh     = (const float*)d_in[9];
    const float* h2oW    = (const float*)d_in[10];
    const float* h2ob    = (const float*)d_in[11];
    const float* octxW   = (const float*)d_in[12];
    const float* octxb   = (const float*)d_in[13];
    const float* o2pW    = (const float*)d_in[14];
    const float* o2pb    = (const float*)d_in[15];
    float* out = (float*)d_out;

    char* base = (char*)d_ws;
    unsigned short* ctxbf  = (unsigned short*)base; base += 25690112L;  // [s][b][c] bf16
    unsigned short* cpbf   = (unsigned short*)base; base += 25690112L;  // [12544][1024]
    unsigned short* c2cT   = (unsigned short*)base; base += 2097152L;   // [n][k]
    unsigned short* attbf  = (unsigned short*)base; base += 2097152L;   // [c][h]
    unsigned short* Wg     = (unsigned short*)base; base += 15728640L;  // packed gates
    unsigned short* h2obf  = (unsigned short*)base; base += 1048576L;
    unsigned short* octxbf = (unsigned short*)base; base += 1048576L;
    unsigned short* o2pbf  = (unsigned short*)base; base += 32768000L;
    unsigned short* xc     = (unsigned short*)base; base += 6225920L;   // [19][64][2560]
    unsigned short* hbf    = (unsigned short*)base; base += 131072L;    // [64][1024]
    unsigned short* obf    = (unsigned short*)base; base += 65536L;     // [64][512]
    float* hf32   = (float*)base; base += 262144L;                      // [64][1024]
    float* hpp    = (float*)base; base += 262144L;                      // [64][1024]
    float* gp1    = (float*)base; base += 1048576L;                     // [64][4096]
    float* gp2    = (float*)base; base += 1048576L;                     // [64][4096]
    float* a2f    = (float*)base; base += 131072L;                      // [64][512]
    float* scb    = (float*)base; base += 50176L;                       // [64][196]
    float* pm     = (float*)base; base += 512000L;                      // [2000][64]
    float* ps     = (float*)base; base += 512000L;
    unsigned* barcnt = (unsigned*)base; base += 256L;

    hipMemsetAsync(d_out, 0, sizeof(float), stream);
    hipMemsetAsync(hf32, 0, 262144, stream);
    hipMemsetAsync(hbf, 0, 131072, stream);
    hipMemsetAsync(xc, 0, 6225920, stream);
    hipMemsetAsync(barcnt, 0, 256, stream);

    // prep
    k_yemb<<<TS_ * 64, 256, 0, stream>>>(y, embW, xc);
    k_tcvt<<<dim3(32, 32), dim3(32, 8), 0, stream>>>(att_c2c, c2cT);
    k_tcvt<<<dim3(32, 32), dim3(32, 8), 0, stream>>>(att_h2c, attbf);
    k_cvt<<<2048, 256, 0, stream>>>(ctx, ctxbf, 12845056L);
    k_cvt<<<512, 256, 0, stream>>>(h2oW, h2obf, 524288L);
    k_cvt<<<512, 256, 0, stream>>>(octxW, octxbf, 524288L);
    k_cvt<<<2048, 256, 0, stream>>>(o2pW, o2pbf, 16384000L);
    k_prepw<<<4096, 256, 0, stream>>>(Wih, Whh, Wg);
    k_gemm<<<392, 512, 0, stream>>>(ctx, c2cT, cpbf);

    // the whole 19-step decoder in one persistent kernel
    k_mega<<<NBLK, NTHR, 0, stream>>>(
        y, mlp, bih, bhh, h2ob, octxb, o2pW, o2pb,
        ctxbf, cpbf, attbf, Wg, h2obf, octxbf, o2pbf,
        xc, hbf, obf, hf32, hpp, gp1, gp2, a2f, scb, pm, ps,
        out, barcnt);
}

// Round 7
// 2154.149 us; speedup vs baseline: 6.7139x; 6.2802x over previous
//
#include <hip/hip_runtime.h>
#include <math.h>

#define TS_ 19   // T-1 decode steps

typedef float f32x4 __attribute__((ext_vector_type(4)));
typedef short s16x8 __attribute__((ext_vector_type(8)));
typedef unsigned short us;

__device__ __forceinline__ float sigmoidf_(float x) { return 1.f / (1.f + __expf(-x)); }

__device__ __forceinline__ float fast_tanh(float x) {
    float ax = fabsf(x);
    float e = __expf(-2.f * ax);
    float r = (1.f - e) * __builtin_amdgcn_rcpf(1.f + e);
    return copysignf(r, x);
}

__device__ __forceinline__ us f2b(float x) {
    union { float f; unsigned u; } v; v.f = x;
    unsigned r = v.u + 0x7fffu + ((v.u >> 16) & 1u);
    return (us)(r >> 16);
}
__device__ __forceinline__ float b2f(us u) {
    union { unsigned u; float f; } v; v.u = ((unsigned)u) << 16; return v.f;
}

#define MFMA(a, b, c) __builtin_amdgcn_mfma_f32_16x16x32_bf16((a), (b), (c), 0, 0, 0)

__device__ __forceinline__ f32x4 zero4() { return (f32x4){0.f, 0.f, 0.f, 0.f}; }

// ---------------- prep kernels ----------------
__global__ __launch_bounds__(256) void k_cvt(const float* __restrict__ in,
                                             us* __restrict__ out, long n) {
    long i = ((long)blockIdx.x * 256 + threadIdx.x) * 4;
    long stride = (long)gridDim.x * 1024;
    for (; i < n; i += stride) {
        float4 v = *(const float4*)(in + i);
        ushort4 o = { f2b(v.x), f2b(v.y), f2b(v.z), f2b(v.w) };
        *(ushort4*)(out + i) = o;
    }
}

__global__ void k_tcvt(const float* __restrict__ in, us* __restrict__ out) {
    __shared__ float tile[32][33];
    int bx = blockIdx.x * 32, by = blockIdx.y * 32;
    int x = threadIdx.x, y0 = threadIdx.y;
    for (int yy = y0; yy < 32; yy += 8) tile[yy][x] = in[(by + yy) * 1024 + bx + x];
    __syncthreads();
    for (int yy = y0; yy < 32; yy += 8) out[(bx + yy) * 1024 + by + x] = f2b(tile[x][yy]);
}

__global__ __launch_bounds__(256) void k_yemb(const int* __restrict__ y,
                                              const float* __restrict__ embW,
                                              us* __restrict__ xc) {
    int t = blockIdx.x >> 6, b = blockIdx.x & 63;
    int row = y[t * 64 + b];
    const float* src = embW + (long)row * 512;
    us* dst = xc + (long)(t * 64 + b) * 2560;
    for (int e = threadIdx.x; e < 512; e += 256) dst[e] = f2b(src[e]);
}

// packed gate weights: rows 0..1023 r (K=2560 = Wih|Whh); 1024..2047 z (K=2560);
// 2048..3071 i_n (K=1536); 3072..4095 h_n (K=1024)
__global__ __launch_bounds__(256) void k_prepw(const float* __restrict__ Wih,
                                               const float* __restrict__ Whh,
                                               us* __restrict__ Wg) {
    int n = blockIdx.x, tid = threadIdx.x;
    int cl = n >> 10;
    if (cl < 2) {
        long base = (long)n * 2560;
        const float* wi = Wih + (long)n * 1536;
        const float* wh = Whh + (long)n * 1024;
        for (int k = tid; k < 1536; k += 256) Wg[base + k] = f2b(wi[k]);
        for (int k = tid; k < 1024; k += 256) Wg[base + 1536 + k] = f2b(wh[k]);
    } else if (cl == 2) {
        long base = 5242880L + (long)(n - 2048) * 1536;
        const float* wi = Wih + (long)n * 1536;
        for (int k = tid; k < 1536; k += 256) Wg[base + k] = f2b(wi[k]);
    } else {
        long base = 6815744L + (long)(n - 3072) * 1024;
        const float* wh = Whh + (long)(n - 1024) * 1024;
        for (int k = tid; k < 1024; k += 256) Wg[base + k] = f2b(wh[k]);
    }
}

// ---------------- ctx_proj GEMM: BM=64 x BN=512, BK=64, dbuf swizzled LDS ------
__global__ __launch_bounds__(512) void k_gemm(const float* __restrict__ A,
                                              const us* __restrict__ Bt,
                                              us* __restrict__ Cb) {
    __shared__ short As[2][4096];
    int tid = threadIdx.x, lane = tid & 63, w = tid >> 6;
    int bm = blockIdx.x % 196, bn = blockIdx.x / 196;
    long m0 = (long)bm * 64;
    int wn0 = bn * 512 + w * 64;
    int mr = lane & 15, kb = lane >> 4;
    int row = tid >> 3, grp = tid & 7;
    int wq = grp ^ (row & 7);
    const float* asrc = A + (m0 + row) * 1024 + grp * 8;

    f32x4 acc[4][4];
#pragma unroll
    for (int i = 0; i < 4; i++)
#pragma unroll
        for (int j = 0; j < 4; j++) acc[i][j] = zero4();

    float4 a0 = *(const float4*)(asrc);
    float4 a1 = *(const float4*)(asrc + 4);
    int buf = 0;
    for (int kt = 0; kt < 16; ++kt) {
        s16x8 pk = { (short)f2b(a0.x), (short)f2b(a0.y), (short)f2b(a0.z), (short)f2b(a0.w),
                     (short)f2b(a1.x), (short)f2b(a1.y), (short)f2b(a1.z), (short)f2b(a1.w) };
        *(s16x8*)&As[buf][row * 64 + wq * 8] = pk;
        __syncthreads();
        if (kt < 15) {
            a0 = *(const float4*)(asrc + (kt + 1) * 64);
            a1 = *(const float4*)(asrc + (kt + 1) * 64 + 4);
        }
#pragma unroll
        for (int ks = 0; ks < 2; ++ks) {
            int xg = ((ks * 4 + kb) ^ (mr & 7)) * 8;
            s16x8 af[4], bfr[4];
#pragma unroll
            for (int mt = 0; mt < 4; ++mt)
                af[mt] = *(s16x8*)&As[buf][(mt * 16 + mr) * 64 + xg];
#pragma unroll
            for (int nt = 0; nt < 4; ++nt)
                bfr[nt] = *(const s16x8*)(Bt + (long)(wn0 + nt * 16 + mr) * 1024 +
                                          kt * 64 + ks * 32 + kb * 8);
#pragma unroll
            for (int mt = 0; mt < 4; ++mt)
#pragma unroll
                for (int nt = 0; nt < 4; ++nt)
                    acc[mt][nt] = MFMA(af[mt], bfr[nt], acc[mt][nt]);
        }
        buf ^= 1;
    }
#pragma unroll
    for (int mt = 0; mt < 4; ++mt)
#pragma unroll
        for (int nt = 0; nt < 4; ++nt)
#pragma unroll
            for (int j = 0; j < 4; ++j)
                Cb[(m0 + mt * 16 + kb * 4 + j) * 1024 + wn0 + nt * 16 + mr] =
                    f2b(acc[mt][nt][j]);
}

// ---------------- hproj parts: hpp[kc][b][n] = (h_t @ attT)_Khalf ----------------
__global__ __launch_bounds__(256) void k_hproj(const us* __restrict__ hcur,
                                               const us* __restrict__ attbf,
                                               float* __restrict__ hpp) {
    int tid = threadIdx.x, lane = tid & 63, w = tid >> 6;
    int vn0 = (blockIdx.x >> 1) * 16, kc = blockIdx.x & 1;
    int m0 = w * 16, mr = lane & 15, kb = lane >> 4;
    const us* ap = hcur + (long)(m0 + mr) * 1024 + kc * 512 + kb * 8;
    const us* bp = attbf + (long)(vn0 + mr) * 1024 + kc * 512 + kb * 8;
    f32x4 acc = zero4();
#pragma unroll 4
    for (int k0 = 0; k0 < 512; k0 += 32)
        acc = MFMA(*(const s16x8*)(ap + k0), *(const s16x8*)(bp + k0), acc);
#pragma unroll
    for (int j = 0; j < 4; ++j)
        hpp[(long)kc * 65536 + (long)(m0 + kb * 4 + j) * 1024 + vn0 + mr] = acc[j];
}

// ---------------- fused attention: scores + softmax + z, one block per b -------
__global__ __launch_bounds__(1024) void k_att(const us* __restrict__ cpbf,
                                              const float* __restrict__ hpp,
                                              const float* __restrict__ mlp,
                                              const us* __restrict__ ctxbf,
                                              us* __restrict__ xc, int t) {
    __shared__ float hp[1024];
    __shared__ float ml[1024];
    __shared__ float scs[200];
    __shared__ float als[200];
    __shared__ float zp[1024];
    int tid = threadIdx.x, b = blockIdx.x;

    // phase 1: combine hproj K-halves; stage mlp
    hp[tid] = hpp[(long)b * 1024 + tid] + hpp[65536 + (long)b * 1024 + tid];
    ml[tid] = mlp[tid];
    __syncthreads();

    // phase 2: scores — 64 groups of 16 threads, each group one s at a time
    {
        int sgrp = tid >> 4, l16 = tid & 15;
        for (int s = sgrp; s < 196; s += 64) {
            const us* cp = cpbf + (long)(s * 64 + b) * 1024 + l16 * 8;
            float acc = 0.f;
#pragma unroll
            for (int k = 0; k < 8; ++k) {
                s16x8 cv = *(const s16x8*)(cp + k * 128);
                int c0 = l16 * 8 + k * 128;
#pragma unroll
                for (int j = 0; j < 8; ++j)
                    acc += fast_tanh(b2f((us)cv[j]) + hp[c0 + j]) * ml[c0 + j];
            }
            acc += __shfl_xor(acc, 1, 64);
            acc += __shfl_xor(acc, 2, 64);
            acc += __shfl_xor(acc, 4, 64);
            acc += __shfl_xor(acc, 8, 64);
            if (l16 == 0) scs[s] = acc;
        }
    }
    __syncthreads();

    // phase 3: softmax (wave 0)
    if (tid < 64) {
        int lane = tid;
        float v0 = scs[lane], v1 = scs[lane + 64], v2 = scs[lane + 128];
        float v3 = (lane < 4) ? scs[192 + lane] : -1e30f;
        float m = fmaxf(fmaxf(v0, v1), fmaxf(v2, v3));
#pragma unroll
        for (int off = 32; off; off >>= 1) m = fmaxf(m, __shfl_xor(m, off, 64));
        float pI = __expf(v0 - m) + __expf(v1 - m) + __expf(v2 - m);
        if (lane < 4) pI += __expf(v3 - m);
#pragma unroll
        for (int off = 32; off; off >>= 1) pI += __shfl_xor(pI, off, 64);
        float inv = 1.f / pI;
        als[lane] = __expf(v0 - m) * inv;
        als[lane + 64] = __expf(v1 - m) * inv;
        als[lane + 128] = __expf(v2 - m) * inv;
        if (lane < 4) als[192 + lane] = __expf(v3 - m) * inv;
    }
    __syncthreads();

    // phase 4: z[c] = sum_s als[s]*ctx[s,b,c]; s-range split across thread halves
    {
        int half = tid >> 9, ct = tid & 511, c0 = ct * 2;
        int sb = half * 98;
        const us* basep = ctxbf + (long)b * 1024 + c0;
        float a0 = 0.f, a1 = 0.f;
        for (int s = sb; s < sb + 98; s += 2) {
            unsigned v0 = *(const unsigned*)(basep + (long)s * 65536);
            unsigned v1 = *(const unsigned*)(basep + (long)(s + 1) * 65536);
            float al0 = als[s], al1 = als[s + 1];
            a0 += al0 * b2f((us)(v0 & 0xffffu)) + al1 * b2f((us)(v1 & 0xffffu));
            a1 += al0 * b2f((us)(v0 >> 16)) + al1 * b2f((us)(v1 >> 16));
        }
        if (half) { zp[ct * 2] = a0; zp[ct * 2 + 1] = a1; }
        __syncthreads();
        if (!half) {
            a0 += zp[ct * 2]; a1 += zp[ct * 2 + 1];
            ushort2 o = { f2b(a0), f2b(a1) };
            *(ushort2*)(xc + (long)(t * 64 + b) * 2560 + 512 + c0) = o;
        }
    }
}

// ---------------- fused GRU: gates GEMM + update, one block per 16-j tile ------
__global__ __launch_bounds__(512) void k_gruh(us* __restrict__ xc,
                                              const us* __restrict__ Wg,
                                              const float* __restrict__ bih,
                                              const float* __restrict__ bhh,
                                              float* __restrict__ hf32,
                                              us* __restrict__ ht_all, int t) {
    __shared__ float lg[8192];   // [kh 2][gate 4][m 64][j 16]
    int tid = threadIdx.x, lane = tid & 63, w = tid >> 6;
    int mr = lane & 15, kb = lane >> 4;
    int mq = w & 3, kh = w >> 2;
    int j0 = blockIdx.x * 16;
    const us* xr = xc + (long)t * 163840 + (long)(mq * 16 + mr) * 2560;

    f32x4 ar_ = zero4(), az_ = zero4(), ai_ = zero4(), ah_ = zero4();
    {   // r and z gates, K-half = 1280 over packed [yemb|z|h]
        const us* ap = xr + kh * 1280 + kb * 8;
        const us* br = Wg + (long)(j0 + mr) * 2560 + kh * 1280 + kb * 8;
        const us* bz = Wg + (long)(1024 + j0 + mr) * 2560 + kh * 1280 + kb * 8;
#pragma unroll 4
        for (int k = 0; k < 1280; k += 32) {
            s16x8 a = *(const s16x8*)(ap + k);
            ar_ = MFMA(a, *(const s16x8*)(br + k), ar_);
            az_ = MFMA(a, *(const s16x8*)(bz + k), az_);
        }
    }
    {   // i_n gate, K-half = 768 over [yemb|z]
        const us* ap = xr + kh * 768 + kb * 8;
        const us* bp = Wg + 5242880L + (long)(j0 + mr) * 1536 + kh * 768 + kb * 8;
#pragma unroll 4
        for (int k = 0; k < 768; k += 32)
            ai_ = MFMA(*(const s16x8*)(ap + k), *(const s16x8*)(bp + k), ai_);
    }
    {   // h_n gate, K-half = 512 over h
        const us* ap = xr + 1536 + kh * 512 + kb * 8;
        const us* bp = Wg + 6815744L + (long)(j0 + mr) * 1024 + kh * 512 + kb * 8;
#pragma unroll 4
        for (int k = 0; k < 512; k += 32)
            ah_ = MFMA(*(const s16x8*)(ap + k), *(const s16x8*)(bp + k), ah_);
    }
#pragma unroll
    for (int j = 0; j < 4; ++j) {
        int m = mq * 16 + kb * 4 + j;
        lg[((kh * 4 + 0) * 64 + m) * 16 + mr] = ar_[j];
        lg[((kh * 4 + 1) * 64 + m) * 16 + mr] = az_[j];
        lg[((kh * 4 + 2) * 64 + m) * 16 + mr] = ai_[j];
        lg[((kh * 4 + 3) * 64 + m) * 16 + mr] = ah_[j];
    }
    __syncthreads();
#pragma unroll
    for (int q = 0; q < 2; ++q) {
        int idx = tid + q * 512;
        int b = idx >> 4, jj = idx & 15;
        int j = j0 + jj;
        float gr = lg[(0 * 64 + b) * 16 + jj] + lg[(4 * 64 + b) * 16 + jj];
        float gz = lg[(1 * 64 + b) * 16 + jj] + lg[(5 * 64 + b) * 16 + jj];
        float gi = lg[(2 * 64 + b) * 16 + jj] + lg[(6 * 64 + b) * 16 + jj];
        float gh = lg[(3 * 64 + b) * 16 + jj] + lg[(7 * 64 + b) * 16 + jj];
        float r  = sigmoidf_(gr + bih[j] + bhh[j]);
        float zz = sigmoidf_(gz + bih[1024 + j] + bhh[1024 + j]);
        float n  = fast_tanh(gi + bih[2048 + j] + r * (gh + bhh[2048 + j]));
        float h = (1.f - zz) * n + zz * hf32[b * 1024 + j];
        hf32[b * 1024 + j] = h;
        us hb = f2b(h);
        ht_all[(long)((t + 1) * 64 + b) * 1024 + j] = hb;
        if (t < TS_ - 1)
            xc[(long)((t + 1) * 64 + b) * 2560 + 1536 + j] = hb;
    }
}

// ---------------- batched output head (all 19 steps): obf_all[1216][512] -------
__global__ __launch_bounds__(512) void k_outb(const us* __restrict__ ht_all,
                                              const us* __restrict__ xc,
                                              const us* __restrict__ h2obf,
                                              const float* __restrict__ h2ob,
                                              const us* __restrict__ octxbf,
                                              const float* __restrict__ octxb,
                                              us* __restrict__ obf_all) {
    int tid = threadIdx.x, lane = tid & 63, w = tid >> 6;
    int mr = lane & 15, kb = lane >> 4;
    int m0 = blockIdx.x * 64;
    int n0 = w * 64;
    f32x4 a1[4][4], a2[4][4];
#pragma unroll
    for (int i = 0; i < 4; i++)
#pragma unroll
        for (int j = 0; j < 4; j++) { a1[i][j] = zero4(); a2[i][j] = zero4(); }

    for (int k0 = 0; k0 < 1024; k0 += 32) {
        s16x8 bf[4], af[4];
#pragma unroll
        for (int nt = 0; nt < 4; ++nt)
            bf[nt] = *(const s16x8*)(h2obf + (long)(n0 + nt * 16 + mr) * 1024 + k0 + kb * 8);
#pragma unroll
        for (int mt = 0; mt < 4; ++mt)
            af[mt] = *(const s16x8*)(ht_all + (long)(64 + m0 + mt * 16 + mr) * 1024 + k0 + kb * 8);
#pragma unroll
        for (int mt = 0; mt < 4; ++mt)
#pragma unroll
            for (int nt = 0; nt < 4; ++nt)
                a1[mt][nt] = MFMA(af[mt], bf[nt], a1[mt][nt]);
    }
    for (int k0 = 0; k0 < 1024; k0 += 32) {
        s16x8 bf[4], af[4];
#pragma unroll
        for (int nt = 0; nt < 4; ++nt)
            bf[nt] = *(const s16x8*)(octxbf + (long)(n0 + nt * 16 + mr) * 1024 + k0 + kb * 8);
#pragma unroll
        for (int mt = 0; mt < 4; ++mt)
            af[mt] = *(const s16x8*)(xc + (long)(m0 + mt * 16 + mr) * 2560 + 512 + k0 + kb * 8);
#pragma unroll
        for (int mt = 0; mt < 4; ++mt)
#pragma unroll
            for (int nt = 0; nt < 4; ++nt)
                a2[mt][nt] = MFMA(af[mt], bf[nt], a2[mt][nt]);
    }
#pragma unroll
    for (int mt = 0; mt < 4; ++mt)
#pragma unroll
        for (int nt = 0; nt < 4; ++nt) {
            int e = n0 + nt * 16 + mr;
            float b1 = h2ob[e], b2 = octxb[e];
#pragma unroll
            for (int j = 0; j < 4; ++j) {
                long row = m0 + mt * 16 + kb * 4 + j;
                float ye = b2f(xc[row * 2560 + e]);
                float val = fast_tanh(a1[mt][nt][j] + b1) + ye + a2[mt][nt][j] + b2;
                obf_all[row * 512 + e] = f2b(fast_tanh(val));
            }
        }
}

// ---------------- batched vocab GEMM + partial LSE: M=1280, N=32000, K=512 -----
__global__ __launch_bounds__(512) void k_vocabb(const us* __restrict__ obf_all,
                                                const us* __restrict__ o2pbf,
                                                const float* __restrict__ o2pb,
                                                float* __restrict__ pm,
                                                float* __restrict__ ps) {
    int tid = threadIdx.x, lane = tid & 63, w = tid >> 6;
    int mr = lane & 15, kb = lane >> 4;
    int mb = blockIdx.x / 125, nb = blockIdx.x % 125;
    int wn = w & 3, mh = w >> 2;
    int m0 = mb * 128 + mh * 64;
    int n0 = nb * 256 + wn * 64;
    f32x4 acc[4][4];
#pragma unroll
    for (int i = 0; i < 4; i++)
#pragma unroll
        for (int j = 0; j < 4; j++) acc[i][j] = zero4();

    for (int k0 = 0; k0 < 512; k0 += 32) {
        s16x8 bf[4], af[4];
#pragma unroll
        for (int nt = 0; nt < 4; ++nt)
            bf[nt] = *(const s16x8*)(o2pbf + (long)(n0 + nt * 16 + mr) * 512 + k0 + kb * 8);
#pragma unroll
        for (int mt = 0; mt < 4; ++mt)
            af[mt] = *(const s16x8*)(obf_all + (long)(m0 + mt * 16 + mr) * 512 + k0 + kb * 8);
#pragma unroll
        for (int mt = 0; mt < 4; ++mt)
#pragma unroll
            for (int nt = 0; nt < 4; ++nt)
                acc[mt][nt] = MFMA(af[mt], bf[nt], acc[mt][nt]);
    }
    float bv[4];
#pragma unroll
    for (int nt = 0; nt < 4; ++nt) bv[nt] = o2pb[n0 + nt * 16 + mr];
#pragma unroll
    for (int mt = 0; mt < 4; ++mt)
#pragma unroll
        for (int j = 0; j < 4; ++j) {
            float x0 = acc[mt][0][j] + bv[0];
            float x1 = acc[mt][1][j] + bv[1];
            float x2 = acc[mt][2][j] + bv[2];
            float x3 = acc[mt][3][j] + bv[3];
            float m = fmaxf(fmaxf(x0, x1), fmaxf(x2, x3));
            float s = __expf(x0 - m) + __expf(x1 - m) + __expf(x2 - m) + __expf(x3 - m);
#pragma unroll
            for (int off = 1; off <= 8; off <<= 1) {
                float mo = __shfl_xor(m, off, 64), so = __shfl_xor(s, off, 64);
                float nm = fmaxf(m, mo);
                s = s * __expf(m - nm) + so * __expf(mo - nm);
                m = nm;
            }
            if (mr == 0) {
                int row = m0 + mt * 16 + kb * 4 + j;
                pm[(long)(nb * 4 + wn) * 1280 + row] = m;
                ps[(long)(nb * 4 + wn) * 1280 + row] = s;
            }
        }
}

// ---------------- final LSE reduce + NLL accumulate ----------------
__global__ __launch_bounds__(64) void k_lseb(const float* __restrict__ pm,
                                             const float* __restrict__ ps,
                                             const us* __restrict__ obf_all,
                                             const float* __restrict__ o2pW,
                                             const float* __restrict__ o2pb,
                                             const int* __restrict__ y,
                                             float* __restrict__ out) {
    int r = blockIdx.x, lane = threadIdx.x;
    int t = r >> 6, b = r & 63;
    int tgt = y[(t + 1) * 64 + b];
    float m = -1e30f, s = 0.f;
    for (int p = lane; p < 500; p += 64) {
        float mi = pm[(long)p * 1280 + r], si = ps[(long)p * 1280 + r];
        float nm = fmaxf(m, mi);
        s = s * __expf(m - nm) + si * __expf(mi - nm);
        m = nm;
    }
#pragma unroll
    for (int off = 32; off; off >>= 1) {
        float mo = __shfl_xor(m, off, 64), so = __shfl_xor(s, off, 64);
        float nm = fmaxf(m, mo);
        s = s * __expf(m - nm) + so * __expf(mo - nm);
        m = nm;
    }
    float d = 0.f;
    const float* wr = o2pW + (long)tgt * 512;
#pragma unroll
    for (int k = 0; k < 8; ++k)
        d += b2f(obf_all[(long)r * 512 + lane + k * 64]) * wr[lane + k * 64];
#pragma unroll
    for (int off = 32; off; off >>= 1) d += __shfl_xor(d, off, 64);
    if (lane == 0 && tgt != 0)
        atomicAdd(out, (m + __logf(s)) - (d + o2pb[tgt]));
}

extern "C" void kernel_launch(void* const* d_in, const int* in_sizes, int n_in,
                              void* d_out, int out_size, void* d_ws, size_t ws_size,
                              hipStream_t stream) {
    const float* ctx     = (const float*)d_in[0];
    const int*   y       = (const int*)d_in[1];
    const float* embW    = (const float*)d_in[2];
    const float* att_c2c = (const float*)d_in[3];
    const float* att_h2c = (const float*)d_in[4];
    const float* mlp     = (const float*)d_in[5];
    const float* Wih     = (const float*)d_in[6];
    const float* bih     = (const float*)d_in[7];
    const float* Whh     = (const float*)d_in[8];
    const float* bhh     = (const float*)d_in[9];
    const float* h2oW    = (const float*)d_in[10];
    const float* h2ob    = (const float*)d_in[11];
    const float* octxW   = (const float*)d_in[12];
    const float* octxb   = (const float*)d_in[13];
    const float* o2pW    = (const float*)d_in[14];
    const float* o2pb    = (const float*)d_in[15];
    float* out = (float*)d_out;

    char* base = (char*)d_ws;
    us* ctxbf   = (us*)base; base += 25690112L;   // [s][b][c] bf16
    us* cpbf    = (us*)base; base += 25690112L;   // [12544][1024]  (pm/ps alias after loop)
    us* c2cT    = (us*)base; base += 2097152L;
    us* attbf   = (us*)base; base += 2097152L;
    us* Wg      = (us*)base; base += 15728640L;
    us* h2obf   = (us*)base; base += 1048576L;
    us* octxbf  = (us*)base; base += 1048576L;
    us* o2pbf   = (us*)base; base += 32768000L;
    us* xc      = (us*)base; base += 6225920L;    // [19][64][2560]
    us* ht_all  = (us*)base; base += 2621440L;    // [20*64][1024], block 0 = h0 = 0
    us* obf_all = (us*)base; base += 1310720L;    // [1280][512]
    float* hf32 = (float*)base; base += 262144L;  // [64][1024]
    float* hpp  = (float*)base; base += 524288L;  // [2][64][1024]
    float* pm   = (float*)cpbf;                   // [500][1280] (aliases cpbf, dead by then)
    float* ps   = pm + 640000L;

    (void)hipMemsetAsync(d_out, 0, sizeof(float), stream);
    (void)hipMemsetAsync(hf32, 0, 262144, stream);
    (void)hipMemsetAsync(ht_all, 0, 131072, stream);                // h0 rows
    (void)hipMemsetAsync(obf_all + 1216L * 512, 0, 65536, stream);  // pad rows
    (void)hipMemsetAsync(xc, 0, 6225920, stream);

    // prep
    k_yemb<<<TS_ * 64, 256, 0, stream>>>(y, embW, xc);
    k_tcvt<<<dim3(32, 32), dim3(32, 8), 0, stream>>>(att_c2c, c2cT);
    k_tcvt<<<dim3(32, 32), dim3(32, 8), 0, stream>>>(att_h2c, attbf);
    k_cvt<<<2048, 256, 0, stream>>>(ctx, ctxbf, 12845056L);
    k_cvt<<<512, 256, 0, stream>>>(h2oW, h2obf, 524288L);
    k_cvt<<<512, 256, 0, stream>>>(octxW, octxbf, 524288L);
    k_cvt<<<2048, 256, 0, stream>>>(o2pW, o2pbf, 16384000L);
    k_prepw<<<4096, 256, 0, stream>>>(Wih, Whh, Wg);
    k_gemm<<<392, 512, 0, stream>>>(ctx, c2cT, cpbf);

    // sequential recurrence: 3 kernels per step
    for (int t = 0; t < TS_; t++) {
        k_hproj<<<128, 256, 0, stream>>>(ht_all + (long)t * 65536, attbf, hpp);
        k_att<<<64, 1024, 0, stream>>>(cpbf, hpp, mlp, ctxbf, xc, t);
        k_gruh<<<64, 512, 0, stream>>>(xc, Wg, bih, bhh, hf32, ht_all, t);
    }

    // deferred output head, batched over all steps
    k_outb<<<19, 512, 0, stream>>>(ht_all, xc, h2obf, h2ob, octxbf, octxb, obf_all);
    k_vocabb<<<1250, 512, 0, stream>>>(obf_all, o2pbf, o2pb, pm, ps);
    k_lseb<<<1216, 64, 0, stream>>>(pm, ps, obf_all, o2pW, o2pb, y, out);
}

// Round 8
// 1349.073 us; speedup vs baseline: 10.7205x; 1.5968x over previous
//
#include <hip/hip_runtime.h>
#include <math.h>

#define TS_ 19   // T-1 decode steps

typedef float f32x4 __attribute__((ext_vector_type(4)));
typedef short s16x8 __attribute__((ext_vector_type(8)));
typedef unsigned short us;

__device__ __forceinline__ float sigmoidf_(float x) { return 1.f / (1.f + __expf(-x)); }

__device__ __forceinline__ float fast_tanh(float x) {
    float ax = fabsf(x);
    float e = __expf(-2.f * ax);
    float r = (1.f - e) * __builtin_amdgcn_rcpf(1.f + e);
    return copysignf(r, x);
}

__device__ __forceinline__ us f2b(float x) {
    union { float f; unsigned u; } v; v.f = x;
    unsigned r = v.u + 0x7fffu + ((v.u >> 16) & 1u);
    return (us)(r >> 16);
}
__device__ __forceinline__ float b2f(us u) {
    union { unsigned u; float f; } v; v.u = ((unsigned)u) << 16; return v.f;
}

#define MFMA(a, b, c) __builtin_amdgcn_mfma_f32_16x16x32_bf16((a), (b), (c), 0, 0, 0)

__device__ __forceinline__ f32x4 zero4() { return (f32x4){0.f, 0.f, 0.f, 0.f}; }

// ---------------- prep kernels ----------------
__global__ __launch_bounds__(256) void k_cvt(const float* __restrict__ in,
                                             us* __restrict__ out, long n) {
    long i = ((long)blockIdx.x * 256 + threadIdx.x) * 4;
    long stride = (long)gridDim.x * 1024;
    for (; i < n; i += stride) {
        float4 v = *(const float4*)(in + i);
        ushort4 o = { f2b(v.x), f2b(v.y), f2b(v.z), f2b(v.w) };
        *(ushort4*)(out + i) = o;
    }
}

__global__ void k_tcvt(const float* __restrict__ in, us* __restrict__ out) {
    __shared__ float tile[32][33];
    int bx = blockIdx.x * 32, by = blockIdx.y * 32;
    int x = threadIdx.x, y0 = threadIdx.y;
    for (int yy = y0; yy < 32; yy += 8) tile[yy][x] = in[(by + yy) * 1024 + bx + x];
    __syncthreads();
    for (int yy = y0; yy < 32; yy += 8) out[(bx + yy) * 1024 + by + x] = f2b(tile[x][yy]);
}

__global__ __launch_bounds__(256) void k_yemb(const int* __restrict__ y,
                                              const float* __restrict__ embW,
                                              us* __restrict__ xc) {
    int t = blockIdx.x >> 6, b = blockIdx.x & 63;
    int row = y[t * 64 + b];
    const float* src = embW + (long)row * 512;
    us* dst = xc + (long)(t * 64 + b) * 2560;
    for (int e = threadIdx.x; e < 512; e += 256) dst[e] = f2b(src[e]);
}

// packed gate weights: rows 0..2047 r/z (K=2560 = Wih|Whh); 2048..3071 i_n (K=1536);
// 3072..4095 h_n (K=1024)
__global__ __launch_bounds__(256) void k_prepw(const float* __restrict__ Wih,
                                               const float* __restrict__ Whh,
                                               us* __restrict__ Wg) {
    int n = blockIdx.x, tid = threadIdx.x;
    int cl = n >> 10;
    if (cl < 2) {
        long base = (long)n * 2560;
        const float* wi = Wih + (long)n * 1536;
        const float* wh = Whh + (long)n * 1024;
        for (int k = tid; k < 1536; k += 256) Wg[base + k] = f2b(wi[k]);
        for (int k = tid; k < 1024; k += 256) Wg[base + 1536 + k] = f2b(wh[k]);
    } else if (cl == 2) {
        long base = 5242880L + (long)(n - 2048) * 1536;
        const float* wi = Wih + (long)n * 1536;
        for (int k = tid; k < 1536; k += 256) Wg[base + k] = f2b(wi[k]);
    } else {
        long base = 6815744L + (long)(n - 3072) * 1024;
        const float* wh = Whh + (long)(n - 1024) * 1024;
        for (int k = tid; k < 1024; k += 256) Wg[base + k] = f2b(wh[k]);
    }
}

// ---------------- ctx_proj GEMM: A=ctxbf (bf16), BM=128 x BN=256, direct stream --
__global__ __launch_bounds__(512) void k_gemm(const us* __restrict__ A,
                                              const us* __restrict__ Bt,
                                              us* __restrict__ Cb) {
    int tid = threadIdx.x, lane = tid & 63, w = tid >> 6;
    int bm = blockIdx.x % 98, bn = blockIdx.x / 98;
    int mr = lane & 15, kb = lane >> 4;
    long m0 = (long)bm * 128 + (w >> 2) * 64;
    int n0 = bn * 256 + (w & 3) * 64;
    const us* ab = A + (m0 + mr) * 1024 + kb * 8;
    const us* bb = Bt + (long)(n0 + mr) * 1024 + kb * 8;

    f32x4 acc[4][4];
#pragma unroll
    for (int i = 0; i < 4; i++)
#pragma unroll
        for (int j = 0; j < 4; j++) acc[i][j] = zero4();

#pragma unroll 4
    for (int k0 = 0; k0 < 1024; k0 += 32) {
        s16x8 af[4], bf[4];
#pragma unroll
        for (int mt = 0; mt < 4; ++mt) af[mt] = *(const s16x8*)(ab + mt * 16384 + k0);
#pragma unroll
        for (int nt = 0; nt < 4; ++nt) bf[nt] = *(const s16x8*)(bb + nt * 16384 + k0);
#pragma unroll
        for (int mt = 0; mt < 4; ++mt)
#pragma unroll
            for (int nt = 0; nt < 4; ++nt)
                acc[mt][nt] = MFMA(af[mt], bf[nt], acc[mt][nt]);
    }
#pragma unroll
    for (int mt = 0; mt < 4; ++mt)
#pragma unroll
        for (int nt = 0; nt < 4; ++nt)
#pragma unroll
            for (int j = 0; j < 4; ++j)
                Cb[(m0 + mt * 16 + kb * 4 + j) * 1024 + n0 + nt * 16 + mr] =
                    f2b(acc[mt][nt][j]);
}

// ---------------- hproj parts: hpp[kc][b][n] = (h_t @ attT)_Khalf ----------------
__global__ __launch_bounds__(256) void k_hproj(const us* __restrict__ hcur,
                                               const us* __restrict__ attbf,
                                               float* __restrict__ hpp) {
    int tid = threadIdx.x, lane = tid & 63, w = tid >> 6;
    int vn0 = (blockIdx.x >> 1) * 16, kc = blockIdx.x & 1;
    int m0 = w * 16, mr = lane & 15, kb = lane >> 4;
    const us* ap = hcur + (long)(m0 + mr) * 1024 + kc * 512 + kb * 8;
    const us* bp = attbf + (long)(vn0 + mr) * 1024 + kc * 512 + kb * 8;
    f32x4 acc = zero4();
#pragma unroll 4
    for (int k0 = 0; k0 < 512; k0 += 32)
        acc = MFMA(*(const s16x8*)(ap + k0), *(const s16x8*)(bp + k0), acc);
#pragma unroll
    for (int j = 0; j < 4; ++j)
        hpp[(long)kc * 65536 + (long)(m0 + kb * 4 + j) * 1024 + vn0 + mr] = acc[j];
}

// ---------------- scores[b][s] = sum_c tanh(cp + hproj)*mlp ----------------
__global__ __launch_bounds__(256) void k_scores(const us* __restrict__ cpb,
                                                const float* __restrict__ hpp,
                                                const float* __restrict__ mlp,
                                                float* __restrict__ scores) {
    __shared__ float hp[1024];
    int tid = threadIdx.x, lane = tid & 63, w = tid >> 6;
    int b = blockIdx.x / 49, s0 = (blockIdx.x % 49) * 4;
    for (int e = tid; e < 1024; e += 256)
        hp[e] = hpp[(long)b * 1024 + e] + hpp[65536 + (long)b * 1024 + e];
    __syncthreads();
    int s = s0 + w;
    const us* cp = cpb + (long)(s * 64 + b) * 1024;
    float acc = 0.f;
#pragma unroll
    for (int i = 0; i < 2; i++) {
        int e0 = i * 512 + lane * 8;
        s16x8 cv = *(const s16x8*)(cp + e0);
        float4 m0v = *(const float4*)(mlp + e0);
        float4 m1v = *(const float4*)(mlp + e0 + 4);
        float mv[8] = {m0v.x, m0v.y, m0v.z, m0v.w, m1v.x, m1v.y, m1v.z, m1v.w};
#pragma unroll
        for (int j = 0; j < 8; j++)
            acc += fast_tanh(b2f((us)cv[j]) + hp[e0 + j]) * mv[j];
    }
#pragma unroll
    for (int off = 32; off; off >>= 1) acc += __shfl_xor(acc, off, 64);
    if (lane == 0) scores[b * 196 + s] = acc;
}

// ---------------- softmax + z -> xc z-slot (bf16 ctx) ----------------
__global__ __launch_bounds__(256) void k_z(const float* __restrict__ scores,
                                           const us* __restrict__ ctxbf,
                                           us* __restrict__ xc, int t) {
    __shared__ float red[256];
    __shared__ float als[196];
    int tid = threadIdx.x, b = blockIdx.x >> 2, ch = blockIdx.x & 3;
    const float* sc = scores + b * 196;
    float lm = -1e30f;
    for (int s = tid; s < 196; s += 256) lm = fmaxf(lm, sc[s]);
    red[tid] = lm; __syncthreads();
    for (int st = 128; st; st >>= 1) { if (tid < st) red[tid] = fmaxf(red[tid], red[tid + st]); __syncthreads(); }
    float m = red[0]; __syncthreads();
    float ls = 0.f;
    for (int s = tid; s < 196; s += 256) ls += __expf(sc[s] - m);
    red[tid] = ls; __syncthreads();
    for (int st = 128; st; st >>= 1) { if (tid < st) red[tid] += red[tid + st]; __syncthreads(); }
    float inv = 1.f / red[0]; __syncthreads();
    for (int s = tid; s < 196; s += 256) als[s] = __expf(sc[s] - m) * inv;
    __syncthreads();
    int c = ch * 256 + tid;
    const us* cp = ctxbf + (long)b * 1024 + c;
    float a0 = 0.f;
    for (int s = 0; s < 196; s += 4) {
#pragma unroll
        for (int u = 0; u < 4; u++)
            a0 += als[s + u] * b2f(cp[(long)(s + u) * 65536]);
    }
    xc[(long)(t * 64 + b) * 2560 + 512 + c] = f2b(a0);
}

// ---------------- GRU gate GEMM (packed virtual N=4096, K-split 2) ----------------
__global__ __launch_bounds__(256) void k_gates(const us* __restrict__ xct,
                                               const us* __restrict__ Wg,
                                               float* __restrict__ gparts) {
    int tid = threadIdx.x, lane = tid & 63, w = tid >> 6;
    int vt = blockIdx.x >> 1, kc = blockIdx.x & 1;
    int vn0 = vt * 16;
    int cl = vn0 >> 10;
    int Kc = (cl < 2) ? 2560 : (cl == 2 ? 1536 : 1024);
    int Kh = Kc >> 1;
    int Aoff = (cl == 3) ? 1536 : 0;
    int m0 = w * 16, mr = lane & 15, kb = lane >> 4;
    int vn = vn0 + mr;
    long rowbase;
    if (cl < 2)       rowbase = (long)vn * 2560;
    else if (cl == 2) rowbase = 5242880L + (long)(vn - 2048) * 1536;
    else              rowbase = 6815744L + (long)(vn - 3072) * 1024;
    const us* ap = xct + (long)(m0 + mr) * 2560 + Aoff + kc * Kh + kb * 8;
    const us* bp = Wg + rowbase + kc * Kh + kb * 8;
    f32x4 acc = zero4();
#pragma unroll 4
    for (int kk = 0; kk < Kh; kk += 32)
        acc = MFMA(*(const s16x8*)(ap + kk), *(const s16x8*)(bp + kk), acc);
#pragma unroll
    for (int j = 0; j < 4; ++j)
        gparts[(long)kc * 262144 + (long)(m0 + kb * 4 + j) * 4096 + vn0 + mr] = acc[j];
}

// ---------------- GRU finish: h' = (1-z)n + z h ; feeds ht_all + next xc --------
__global__ __launch_bounds__(256) void k_hfin(const float* __restrict__ gp,
                                              const float* __restrict__ bih,
                                              const float* __restrict__ bhh,
                                              float* __restrict__ hf32,
                                              us* __restrict__ ht_all,
                                              us* __restrict__ xc, int t) {
    int i = blockIdx.x * 256 + threadIdx.x;
    int b = i >> 10, j = i & 1023;
    const float* g0 = gp + (long)b * 4096;
    const float* g1 = gp + 262144 + (long)b * 4096;
    float r  = sigmoidf_(g0[j] + g1[j] + bih[j] + bhh[j]);
    float zz = sigmoidf_(g0[1024 + j] + g1[1024 + j] + bih[1024 + j] + bhh[1024 + j]);
    float n  = fast_tanh(g0[2048 + j] + g1[2048 + j] + bih[2048 + j] +
                         r * (g0[3072 + j] + g1[3072 + j] + bhh[2048 + j]));
    float h = (1.f - zz) * n + zz * hf32[i];
    hf32[i] = h;
    us hb = f2b(h);
    ht_all[(long)((t + 1) * 64 + b) * 1024 + j] = hb;
    if (t < TS_ - 1) xc[(long)((t + 1) * 64 + b) * 2560 + 1536 + j] = hb;
}

// ---------------- batched output head (all 19 steps): obf_all[1216][512] -------
__global__ __launch_bounds__(256) void k_outb(const us* __restrict__ ht_all,
                                              const us* __restrict__ xc,
                                              const us* __restrict__ h2obf,
                                              const float* __restrict__ h2ob,
                                              const us* __restrict__ octxbf,
                                              const float* __restrict__ octxb,
                                              us* __restrict__ obf_all) {
    int tid = threadIdx.x, lane = tid & 63, w = tid >> 6;
    int mr = lane & 15, kb = lane >> 4;
    int m0 = blockIdx.x * 64;
    int n0 = blockIdx.y * 256 + w * 64;
    f32x4 a1[4][4], a2[4][4];
#pragma unroll
    for (int i = 0; i < 4; i++)
#pragma unroll
        for (int j = 0; j < 4; j++) { a1[i][j] = zero4(); a2[i][j] = zero4(); }

    for (int k0 = 0; k0 < 1024; k0 += 32) {
        s16x8 bf[4], af[4];
#pragma unroll
        for (int nt = 0; nt < 4; ++nt)
            bf[nt] = *(const s16x8*)(h2obf + (long)(n0 + nt * 16 + mr) * 1024 + k0 + kb * 8);
#pragma unroll
        for (int mt = 0; mt < 4; ++mt)
            af[mt] = *(const s16x8*)(ht_all + (long)(64 + m0 + mt * 16 + mr) * 1024 + k0 + kb * 8);
#pragma unroll
        for (int mt = 0; mt < 4; ++mt)
#pragma unroll
            for (int nt = 0; nt < 4; ++nt)
                a1[mt][nt] = MFMA(af[mt], bf[nt], a1[mt][nt]);
    }
    for (int k0 = 0; k0 < 1024; k0 += 32) {
        s16x8 bf[4], af[4];
#pragma unroll
        for (int nt = 0; nt < 4; ++nt)
            bf[nt] = *(const s16x8*)(octxbf + (long)(n0 + nt * 16 + mr) * 1024 + k0 + kb * 8);
#pragma unroll
        for (int mt = 0; mt < 4; ++mt)
            af[mt] = *(const s16x8*)(xc + (long)(m0 + mt * 16 + mr) * 2560 + 512 + k0 + kb * 8);
#pragma unroll
        for (int mt = 0; mt < 4; ++mt)
#pragma unroll
            for (int nt = 0; nt < 4; ++nt)
                a2[mt][nt] = MFMA(af[mt], bf[nt], a2[mt][nt]);
    }
#pragma unroll
    for (int mt = 0; mt < 4; ++mt)
#pragma unroll
        for (int nt = 0; nt < 4; ++nt) {
            int e = n0 + nt * 16 + mr;
            float b1 = h2ob[e], b2 = octxb[e];
#pragma unroll
            for (int j = 0; j < 4; ++j) {
                long row = m0 + mt * 16 + kb * 4 + j;
                float ye = b2f(xc[row * 2560 + e]);
                float val = fast_tanh(a1[mt][nt][j] + b1) + ye + a2[mt][nt][j] + b2;
                obf_all[(row << 9) + e] = f2b(fast_tanh(val));
            }
        }
}

// ---------------- batched vocab GEMM + partial LSE: weight-reuse geometry -------
// block: 128 n x 256 m; mb innermost in blockIdx for L2/L3 weight reuse.
__global__ __launch_bounds__(512) void k_vocabb(const us* __restrict__ obf_all,
                                                const us* __restrict__ o2pbf,
                                                const float* __restrict__ o2pb,
                                                float* __restrict__ pm,
                                                float* __restrict__ ps) {
    int tid = threadIdx.x, lane = tid & 63, w = tid >> 6;
    int mr = lane & 15, kb = lane >> 4;
    int mb = blockIdx.x % 5, nb = blockIdx.x / 5;
    int wn = w & 1, wm = w >> 1;
    int m0 = mb * 256 + wm * 64;
    int n0 = nb * 128 + wn * 64;
    const us* ab = obf_all + (long)(m0 + mr) * 512 + kb * 8;
    const us* bb = o2pbf + (long)(n0 + mr) * 512 + kb * 8;
    f32x4 acc[4][4];
#pragma unroll
    for (int i = 0; i < 4; i++)
#pragma unroll
        for (int j = 0; j < 4; j++) acc[i][j] = zero4();

#pragma unroll 2
    for (int k0 = 0; k0 < 512; k0 += 32) {
        s16x8 bf[4], af[4];
#pragma unroll
        for (int nt = 0; nt < 4; ++nt) bf[nt] = *(const s16x8*)(bb + nt * 8192 + k0);
#pragma unroll
        for (int mt = 0; mt < 4; ++mt) af[mt] = *(const s16x8*)(ab + mt * 8192 + k0);
#pragma unroll
        for (int mt = 0; mt < 4; ++mt)
#pragma unroll
            for (int nt = 0; nt < 4; ++nt)
                acc[mt][nt] = MFMA(af[mt], bf[nt], acc[mt][nt]);
    }
    float bv[4];
#pragma unroll
    for (int nt = 0; nt < 4; ++nt) bv[nt] = o2pb[n0 + nt * 16 + mr];
#pragma unroll
    for (int mt = 0; mt < 4; ++mt)
#pragma unroll
        for (int j = 0; j < 4; ++j) {
            float x0 = acc[mt][0][j] + bv[0];
            float x1 = acc[mt][1][j] + bv[1];
            float x2 = acc[mt][2][j] + bv[2];
            float x3 = acc[mt][3][j] + bv[3];
            float m = fmaxf(fmaxf(x0, x1), fmaxf(x2, x3));
            float s = __expf(x0 - m) + __expf(x1 - m) + __expf(x2 - m) + __expf(x3 - m);
#pragma unroll
            for (int off = 1; off <= 8; off <<= 1) {
                float mo = __shfl_xor(m, off, 64), so = __shfl_xor(s, off, 64);
                float nm = fmaxf(m, mo);
                s = s * __expf(m - nm) + so * __expf(mo - nm);
                m = nm;
            }
            if (mr == 0) {
                int row = m0 + mt * 16 + kb * 4 + j;
                pm[(long)(nb * 2 + wn) * 1280 + row] = m;
                ps[(long)(nb * 2 + wn) * 1280 + row] = s;
            }
        }
}

// ---------------- final LSE reduce + NLL accumulate ----------------
__global__ __launch_bounds__(64) void k_lseb(const float* __restrict__ pm,
                                             const float* __restrict__ ps,
                                             const us* __restrict__ obf_all,
                                             const float* __restrict__ o2pW,
                                             const float* __restrict__ o2pb,
                                             const int* __restrict__ y,
                                             float* __restrict__ out) {
    int r = blockIdx.x, lane = threadIdx.x;
    int t = r >> 6, b = r & 63;
    int tgt = y[(t + 1) * 64 + b];
    float m = -1e30f, s = 0.f;
    for (int p = lane; p < 500; p += 64) {
        float mi = pm[(long)p * 1280 + r], si = ps[(long)p * 1280 + r];
        float nm = fmaxf(m, mi);
        s = s * __expf(m - nm) + si * __expf(mi - nm);
        m = nm;
    }
#pragma unroll
    for (int off = 32; off; off >>= 1) {
        float mo = __shfl_xor(m, off, 64), so = __shfl_xor(s, off, 64);
        float nm = fmaxf(m, mo);
        s = s * __expf(m - nm) + so * __expf(mo - nm);
        m = nm;
    }
    float d = 0.f;
    const float* wr = o2pW + (long)tgt * 512;
#pragma unroll
    for (int k = 0; k < 8; ++k)
        d += b2f(obf_all[(long)r * 512 + lane + k * 64]) * wr[lane + k * 64];
#pragma unroll
    for (int off = 32; off; off >>= 1) d += __shfl_xor(d, off, 64);
    if (lane == 0 && tgt != 0)
        atomicAdd(out, (m + __logf(s)) - (d + o2pb[tgt]));
}

extern "C" void kernel_launch(void* const* d_in, const int* in_sizes, int n_in,
                              void* d_out, int out_size, void* d_ws, size_t ws_size,
                              hipStream_t stream) {
    const float* ctx     = (const float*)d_in[0];
    const int*   y       = (const int*)d_in[1];
    const float* embW    = (const float*)d_in[2];
    const float* att_c2c = (const float*)d_in[3];
    const float* att_h2c = (const float*)d_in[4];
    const float* mlp     = (const float*)d_in[5];
    const float* Wih     = (const float*)d_in[6];
    const float* bih     = (const float*)d_in[7];
    const float* Whh     = (const float*)d_in[8];
    const float* bhh     = (const float*)d_in[9];
    const float* h2oW    = (const float*)d_in[10];
    const float* h2ob    = (const float*)d_in[11];
    const float* octxW   = (const float*)d_in[12];
    const float* octxb   = (const float*)d_in[13];
    const float* o2pW    = (const float*)d_in[14];
    const float* o2pb    = (const float*)d_in[15];
    float* out = (float*)d_out;

    char* base = (char*)d_ws;
    us* ctxbf   = (us*)base; base += 25690112L;   // [s][b][c] bf16 (= GEMM A)
    us* cpbf    = (us*)base; base += 25690112L;   // [12544][1024]; pm/ps alias after loop
    us* c2cT    = (us*)base; base += 2097152L;
    us* attbf   = (us*)base; base += 2097152L;
    us* Wg      = (us*)base; base += 15728640L;
    us* h2obf   = (us*)base; base += 1048576L;
    us* octxbf  = (us*)base; base += 1048576L;
    us* o2pbf   = (us*)base; base += 32768000L;
    us* xc      = (us*)base; base += 6225920L;    // [19][64][2560]
    us* ht_all  = (us*)base; base += 2621440L;    // [20*64][1024], rows 0..63 = h0 = 0
    us* obf_all = (us*)base; base += 1310720L;    // [1280][512], rows 1216+ zero pad
    float* hf32   = (float*)base; base += 262144L;  // [64][1024]
    float* hpp    = (float*)base; base += 524288L;  // [2][64][1024]
    float* gparts = (float*)base; base += 2097152L; // [2][64][4096]
    float* scb    = (float*)base; base += 50176L;   // [64][196]
    float* pm   = (float*)cpbf;                   // [500][1280] aliases cpbf (dead by then)
    float* ps   = pm + 640000L;

    (void)hipMemsetAsync(d_out, 0, sizeof(float), stream);
    (void)hipMemsetAsync(hf32, 0, 262144, stream);
    (void)hipMemsetAsync(ht_all, 0, 131072, stream);                // h0 rows
    (void)hipMemsetAsync(obf_all + 1216L * 512, 0, 65536, stream);  // pad rows
    (void)hipMemsetAsync(xc, 0, 6225920, stream);

    // prep
    k_yemb<<<TS_ * 64, 256, 0, stream>>>(y, embW, xc);
    k_tcvt<<<dim3(32, 32), dim3(32, 8), 0, stream>>>(att_c2c, c2cT);
    k_tcvt<<<dim3(32, 32), dim3(32, 8), 0, stream>>>(att_h2c, attbf);
    k_cvt<<<2048, 256, 0, stream>>>(ctx, ctxbf, 12845056L);
    k_cvt<<<512, 256, 0, stream>>>(h2oW, h2obf, 524288L);
    k_cvt<<<512, 256, 0, stream>>>(octxW, octxbf, 524288L);
    k_cvt<<<2048, 256, 0, stream>>>(o2pW, o2pbf, 16384000L);
    k_prepw<<<4096, 256, 0, stream>>>(Wih, Whh, Wg);
    k_gemm<<<392, 512, 0, stream>>>(ctxbf, c2cT, cpbf);

    // sequential recurrence: 5 well-parallelized kernels per step
    for (int t = 0; t < TS_; t++) {
        const us* xct = xc + (long)t * 163840;
        k_hproj<<<128, 256, 0, stream>>>(ht_all + (long)t * 65536, attbf, hpp);
        k_scores<<<3136, 256, 0, stream>>>(cpbf, hpp, mlp, scb);
        k_z<<<256, 256, 0, stream>>>(scb, ctxbf, xc, t);
        k_gates<<<512, 256, 0, stream>>>(xct, Wg, gparts);
        k_hfin<<<256, 256, 0, stream>>>(gparts, bih, bhh, hf32, ht_all, xc, t);
    }

    // deferred output head, batched over all steps
    k_outb<<<dim3(19, 2), 256, 0, stream>>>(ht_all, xc, h2obf, h2ob, octxbf, octxb, obf_all);
    k_vocabb<<<1250, 512, 0, stream>>>(obf_all, o2pbf, o2pb, pm, ps);
    k_lseb<<<1216, 64, 0, stream>>>(pm, ps, obf_all, o2pW, o2pb, y, out);
}

// Round 9
// 1272.021 us; speedup vs baseline: 11.3699x; 1.0606x over previous
//
#include <hip/hip_runtime.h>
#include <math.h>

#define TS_ 19   // T-1 decode steps

typedef float f32x4 __attribute__((ext_vector_type(4)));
typedef short s16x8 __attribute__((ext_vector_type(8)));
typedef unsigned short us;

__device__ __forceinline__ float sigmoidf_(float x) { return 1.f / (1.f + __expf(-x)); }

__device__ __forceinline__ float fast_tanh(float x) {
    float ax = fabsf(x);
    float e = __expf(-2.f * ax);
    float r = (1.f - e) * __builtin_amdgcn_rcpf(1.f + e);
    return copysignf(r, x);
}

__device__ __forceinline__ us f2b(float x) {
    union { float f; unsigned u; } v; v.f = x;
    unsigned r = v.u + 0x7fffu + ((v.u >> 16) & 1u);
    return (us)(r >> 16);
}
__device__ __forceinline__ float b2f(us u) {
    union { unsigned u; float f; } v; v.u = ((unsigned)u) << 16; return v.f;
}

#define MFMA(a, b, c) __builtin_amdgcn_mfma_f32_16x16x32_bf16((a), (b), (c), 0, 0, 0)

__device__ __forceinline__ f32x4 zero4() { return (f32x4){0.f, 0.f, 0.f, 0.f}; }

__device__ __forceinline__ f32x4 wg16(const us* ap, const us* bp, int nk, f32x4 acc) {
#pragma unroll 4
    for (int k = 0; k < nk; k += 32)
        acc = MFMA(*(const s16x8*)(ap + k), *(const s16x8*)(bp + k), acc);
    return acc;
}

// ---------------- prep kernels ----------------
__global__ __launch_bounds__(256) void k_cvt(const float* __restrict__ in,
                                             us* __restrict__ out, long n) {
    long i = ((long)blockIdx.x * 256 + threadIdx.x) * 4;
    long stride = (long)gridDim.x * 1024;
    for (; i < n; i += stride) {
        float4 v = *(const float4*)(in + i);
        ushort4 o = { f2b(v.x), f2b(v.y), f2b(v.z), f2b(v.w) };
        *(ushort4*)(out + i) = o;
    }
}

__global__ void k_tcvt(const float* __restrict__ in, us* __restrict__ out) {
    __shared__ float tile[32][33];
    int bx = blockIdx.x * 32, by = blockIdx.y * 32;
    int x = threadIdx.x, y0 = threadIdx.y;
    for (int yy = y0; yy < 32; yy += 8) tile[yy][x] = in[(by + yy) * 1024 + bx + x];
    __syncthreads();
    for (int yy = y0; yy < 32; yy += 8) out[(bx + yy) * 1024 + by + x] = f2b(tile[x][yy]);
}

__global__ __launch_bounds__(256) void k_yemb(const int* __restrict__ y,
                                              const float* __restrict__ embW,
                                              us* __restrict__ xc) {
    int t = blockIdx.x >> 6, b = blockIdx.x & 63;
    int row = y[t * 64 + b];
    const float* src = embW + (long)row * 512;
    us* dst = xc + (long)(t * 64 + b) * 2560;
    for (int e = threadIdx.x; e < 512; e += 256) dst[e] = f2b(src[e]);
}

// packed gate weights: rows 0..2047 r/z (K=2560 = Wih|Whh); 2048..3071 i_n (K=1536);
// 3072..4095 h_n (K=1024)
__global__ __launch_bounds__(256) void k_prepw(const float* __restrict__ Wih,
                                               const float* __restrict__ Whh,
                                               us* __restrict__ Wg) {
    int n = blockIdx.x, tid = threadIdx.x;
    int cl = n >> 10;
    if (cl < 2) {
        long base = (long)n * 2560;
        const float* wi = Wih + (long)n * 1536;
        const float* wh = Whh + (long)n * 1024;
        for (int k = tid; k < 1536; k += 256) Wg[base + k] = f2b(wi[k]);
        for (int k = tid; k < 1024; k += 256) Wg[base + 1536 + k] = f2b(wh[k]);
    } else if (cl == 2) {
        long base = 5242880L + (long)(n - 2048) * 1536;
        const float* wi = Wih + (long)n * 1536;
        for (int k = tid; k < 1536; k += 256) Wg[base + k] = f2b(wi[k]);
    } else {
        long base = 6815744L + (long)(n - 3072) * 1024;
        const float* wh = Whh + (long)(n - 1024) * 1024;
        for (int k = tid; k < 1024; k += 256) Wg[base + k] = f2b(wh[k]);
    }
}

// ---------------- ctx_proj GEMM: A=ctxbf (bf16), BM=128 x BN=256, direct stream --
__global__ __launch_bounds__(512) void k_gemm(const us* __restrict__ A,
                                              const us* __restrict__ Bt,
                                              us* __restrict__ Cb) {
    int tid = threadIdx.x, lane = tid & 63, w = tid >> 6;
    int bm = blockIdx.x % 98, bn = blockIdx.x / 98;
    int mr = lane & 15, kb = lane >> 4;
    long m0 = (long)bm * 128 + (w >> 2) * 64;
    int n0 = bn * 256 + (w & 3) * 64;
    const us* ab = A + (m0 + mr) * 1024 + kb * 8;
    const us* bb = Bt + (long)(n0 + mr) * 1024 + kb * 8;

    f32x4 acc[4][4];
#pragma unroll
    for (int i = 0; i < 4; i++)
#pragma unroll
        for (int j = 0; j < 4; j++) acc[i][j] = zero4();

#pragma unroll 4
    for (int k0 = 0; k0 < 1024; k0 += 32) {
        s16x8 af[4], bf[4];
#pragma unroll
        for (int mt = 0; mt < 4; ++mt) af[mt] = *(const s16x8*)(ab + mt * 16384 + k0);
#pragma unroll
        for (int nt = 0; nt < 4; ++nt) bf[nt] = *(const s16x8*)(bb + nt * 16384 + k0);
#pragma unroll
        for (int mt = 0; mt < 4; ++mt)
#pragma unroll
            for (int nt = 0; nt < 4; ++nt)
                acc[mt][nt] = MFMA(af[mt], bf[nt], acc[mt][nt]);
    }
#pragma unroll
    for (int mt = 0; mt < 4; ++mt)
#pragma unroll
        for (int nt = 0; nt < 4; ++nt)
#pragma unroll
            for (int j = 0; j < 4; ++j)
                Cb[(m0 + mt * 16 + kb * 4 + j) * 1024 + n0 + nt * 16 + mr] =
                    f2b(acc[mt][nt][j]);
}

// ---------------- hproj parts: hpp[kc][b][n] = (h_t @ attT)_Khalf ----------------
__global__ __launch_bounds__(256) void k_hproj(const us* __restrict__ hcur,
                                               const us* __restrict__ attbf,
                                               float* __restrict__ hpp) {
    int tid = threadIdx.x, lane = tid & 63, w = tid >> 6;
    int vn0 = (blockIdx.x >> 1) * 16, kc = blockIdx.x & 1;
    int m0 = w * 16, mr = lane & 15, kb = lane >> 4;
    const us* ap = hcur + (long)(m0 + mr) * 1024 + kc * 512 + kb * 8;
    const us* bp = attbf + (long)(vn0 + mr) * 1024 + kc * 512 + kb * 8;
    f32x4 acc = wg16(ap, bp, 512, zero4());
#pragma unroll
    for (int j = 0; j < 4; ++j)
        hpp[(long)kc * 65536 + (long)(m0 + kb * 4 + j) * 1024 + vn0 + mr] = acc[j];
}

// ---------------- scores[b][s] = sum_c tanh(cp + hproj)*mlp ----------------
__global__ __launch_bounds__(256) void k_scores(const us* __restrict__ cpb,
                                                const float* __restrict__ hpp,
                                                const float* __restrict__ mlp,
                                                float* __restrict__ scores) {
    __shared__ float hp[1024];
    int tid = threadIdx.x, lane = tid & 63, w = tid >> 6;
    int b = blockIdx.x / 49, s0 = (blockIdx.x % 49) * 4;
    for (int e = tid; e < 1024; e += 256)
        hp[e] = hpp[(long)b * 1024 + e] + hpp[65536 + (long)b * 1024 + e];
    __syncthreads();
    int s = s0 + w;
    const us* cp = cpb + (long)(s * 64 + b) * 1024;
    float acc = 0.f;
#pragma unroll
    for (int i = 0; i < 2; i++) {
        int e0 = i * 512 + lane * 8;
        s16x8 cv = *(const s16x8*)(cp + e0);
        float4 m0v = *(const float4*)(mlp + e0);
        float4 m1v = *(const float4*)(mlp + e0 + 4);
        float mv[8] = {m0v.x, m0v.y, m0v.z, m0v.w, m1v.x, m1v.y, m1v.z, m1v.w};
#pragma unroll
        for (int j = 0; j < 8; j++)
            acc += fast_tanh(b2f((us)cv[j]) + hp[e0 + j]) * mv[j];
    }
#pragma unroll
    for (int off = 32; off; off >>= 1) acc += __shfl_xor(acc, off, 64);
    if (lane == 0) scores[b * 196 + s] = acc;
}

// ---------------- softmax + z -> xc z-slot; 512 thr, s-split halves ----------
__global__ __launch_bounds__(512) void k_z(const float* __restrict__ scores,
                                           const us* __restrict__ ctxbf,
                                           us* __restrict__ xc, int t) {
    __shared__ float red[512];
    __shared__ float als[196];
    __shared__ float zp[256];
    int tid = threadIdx.x, b = blockIdx.x >> 2, ch = blockIdx.x & 3;
    const float* sc = scores + b * 196;
    float lm = (tid < 196) ? sc[tid] : -1e30f;
    red[tid] = lm; __syncthreads();
    for (int st = 256; st; st >>= 1) { if (tid < st) red[tid] = fmaxf(red[tid], red[tid + st]); __syncthreads(); }
    float m = red[0]; __syncthreads();
    float ls = (tid < 196) ? __expf(sc[tid] - m) : 0.f;
    red[tid] = ls; __syncthreads();
    for (int st = 256; st; st >>= 1) { if (tid < st) red[tid] += red[tid + st]; __syncthreads(); }
    float inv = 1.f / red[0];
    if (tid < 196) als[tid] = ls * inv;
    __syncthreads();
    int c = ch * 256 + (tid & 255);
    int sh = tid >> 8;
    const us* cp = ctxbf + (long)b * 1024 + c;
    float a0 = 0.f;
    int sb = sh * 98;
    for (int s = sb; s < sb + 98; s += 2) {
        a0 += als[s] * b2f(cp[(long)s * 65536]) +
              als[s + 1] * b2f(cp[(long)(s + 1) * 65536]);
    }
    if (sh) zp[tid & 255] = a0;
    __syncthreads();
    if (!sh) {
        a0 += zp[tid & 255];
        xc[(long)(t * 64 + b) * 2560 + 512 + c] = f2b(a0);
    }
}

// ---------------- fused GRU: all 4 gates + update, one block per (j16, m16) ----
// 8 waves: gate g = w>>1, K-half kh = w&1; LDS combine; epilogue updates h.
__global__ __launch_bounds__(512) void k_gruh2(us* __restrict__ xc,
                                               const us* __restrict__ Wg,
                                               const float* __restrict__ bih,
                                               const float* __restrict__ bhh,
                                               float* __restrict__ hf32,
                                               us* __restrict__ ht_all, int t) {
    __shared__ float lg[2048];   // [g*2+kh][m16][j16]
    int tid = threadIdx.x, lane = tid & 63, w = tid >> 6;
    int mr = lane & 15, kb = lane >> 4;
    int g = w >> 1, kh = w & 1;
    int mq = blockIdx.x & 3, jt = blockIdx.x >> 2;
    int m0 = mq * 16, j0 = jt * 16;
    const us* xr = xc + (long)t * 163840 + (long)(m0 + mr) * 2560;

    f32x4 acc = zero4();
    if (g == 0) {
        acc = wg16(xr + kh * 1280 + kb * 8,
                   Wg + (long)(j0 + mr) * 2560 + kh * 1280 + kb * 8, 1280, acc);
    } else if (g == 1) {
        acc = wg16(xr + kh * 1280 + kb * 8,
                   Wg + (long)(1024 + j0 + mr) * 2560 + kh * 1280 + kb * 8, 1280, acc);
    } else if (g == 2) {
        acc = wg16(xr + kh * 768 + kb * 8,
                   Wg + 5242880L + (long)(j0 + mr) * 1536 + kh * 768 + kb * 8, 768, acc);
    } else {
        acc = wg16(xr + 1536 + kh * 512 + kb * 8,
                   Wg + 6815744L + (long)(j0 + mr) * 1024 + kh * 512 + kb * 8, 512, acc);
    }
#pragma unroll
    for (int j = 0; j < 4; ++j)
        lg[(g * 2 + kh) * 256 + (kb * 4 + j) * 16 + mr] = acc[j];
    __syncthreads();

    if (tid < 256) {
        int ml = tid >> 4, jj = tid & 15;
        int b = m0 + ml, j = j0 + jj;
        float gr = lg[0 * 256 + ml * 16 + jj] + lg[1 * 256 + ml * 16 + jj];
        float gz = lg[2 * 256 + ml * 16 + jj] + lg[3 * 256 + ml * 16 + jj];
        float gi = lg[4 * 256 + ml * 16 + jj] + lg[5 * 256 + ml * 16 + jj];
        float gh = lg[6 * 256 + ml * 16 + jj] + lg[7 * 256 + ml * 16 + jj];
        float r  = sigmoidf_(gr + bih[j] + bhh[j]);
        float zz = sigmoidf_(gz + bih[1024 + j] + bhh[1024 + j]);
        float n  = fast_tanh(gi + bih[2048 + j] + r * (gh + bhh[2048 + j]));
        float h = (1.f - zz) * n + zz * hf32[b * 1024 + j];
        hf32[b * 1024 + j] = h;
        us hb = f2b(h);
        ht_all[(long)((t + 1) * 64 + b) * 1024 + j] = hb;
        if (t < TS_ - 1) xc[(long)((t + 1) * 64 + b) * 2560 + 1536 + j] = hb;
    }
}

// ---------------- batched output head (all 19 steps): obf_all[1216][512] -------
__global__ __launch_bounds__(256) void k_outb(const us* __restrict__ ht_all,
                                              const us* __restrict__ xc,
                                              const us* __restrict__ h2obf,
                                              const float* __restrict__ h2ob,
                                              const us* __restrict__ octxbf,
                                              const float* __restrict__ octxb,
                                              us* __restrict__ obf_all) {
    int tid = threadIdx.x, lane = tid & 63, w = tid >> 6;
    int mr = lane & 15, kb = lane >> 4;
    int m0 = blockIdx.x * 64;
    int n0 = blockIdx.y * 256 + w * 64;
    f32x4 a1[4][4], a2[4][4];
#pragma unroll
    for (int i = 0; i < 4; i++)
#pragma unroll
        for (int j = 0; j < 4; j++) { a1[i][j] = zero4(); a2[i][j] = zero4(); }

    for (int k0 = 0; k0 < 1024; k0 += 32) {
        s16x8 bf[4], af[4];
#pragma unroll
        for (int nt = 0; nt < 4; ++nt)
            bf[nt] = *(const s16x8*)(h2obf + (long)(n0 + nt * 16 + mr) * 1024 + k0 + kb * 8);
#pragma unroll
        for (int mt = 0; mt < 4; ++mt)
            af[mt] = *(const s16x8*)(ht_all + (long)(64 + m0 + mt * 16 + mr) * 1024 + k0 + kb * 8);
#pragma unroll
        for (int mt = 0; mt < 4; ++mt)
#pragma unroll
            for (int nt = 0; nt < 4; ++nt)
                a1[mt][nt] = MFMA(af[mt], bf[nt], a1[mt][nt]);
    }
    for (int k0 = 0; k0 < 1024; k0 += 32) {
        s16x8 bf[4], af[4];
#pragma unroll
        for (int nt = 0; nt < 4; ++nt)
            bf[nt] = *(const s16x8*)(octxbf + (long)(n0 + nt * 16 + mr) * 1024 + k0 + kb * 8);
#pragma unroll
        for (int mt = 0; mt < 4; ++mt)
            af[mt] = *(const s16x8*)(xc + (long)(m0 + mt * 16 + mr) * 2560 + 512 + k0 + kb * 8);
#pragma unroll
        for (int mt = 0; mt < 4; ++mt)
#pragma unroll
            for (int nt = 0; nt < 4; ++nt)
                a2[mt][nt] = MFMA(af[mt], bf[nt], a2[mt][nt]);
    }
#pragma unroll
    for (int mt = 0; mt < 4; ++mt)
#pragma unroll
        for (int nt = 0; nt < 4; ++nt) {
            int e = n0 + nt * 16 + mr;
            float b1 = h2ob[e], b2 = octxb[e];
#pragma unroll
            for (int j = 0; j < 4; ++j) {
                long row = m0 + mt * 16 + kb * 4 + j;
                float ye = b2f(xc[row * 2560 + e]);
                float val = fast_tanh(a1[mt][nt][j] + b1) + ye + a2[mt][nt][j] + b2;
                obf_all[(row << 9) + e] = f2b(fast_tanh(val));
            }
        }
}

// ---------------- batched vocab GEMM + partial LSE: persistent-N geometry ------
// grid = 250 n-blocks; each block loops over all 5 m-tiles so its 128-row weight
// slice is fetched from L3 once (L2-hits across m-iters). 1024 thr = 16 waves.
__global__ __launch_bounds__(1024) void k_vocabb(const us* __restrict__ obf_all,
                                                 const us* __restrict__ o2pbf,
                                                 const float* __restrict__ o2pb,
                                                 float* __restrict__ pm,
                                                 float* __restrict__ ps) {
    int tid = threadIdx.x, lane = tid & 63, w = tid >> 6;
    int mr = lane & 15, kb = lane >> 4;
    int nb = blockIdx.x;
    int wm = w >> 1, wn = w & 1;
    int n0 = nb * 128 + wn * 64;
    const us* bb = o2pbf + (long)(n0 + mr) * 512 + kb * 8;
    float bv[4];
#pragma unroll
    for (int nt = 0; nt < 4; ++nt) bv[nt] = o2pb[n0 + nt * 16 + mr];

    for (int mi = 0; mi < 5; ++mi) {
        int m0 = mi * 256 + wm * 32;
        const us* ab = obf_all + (long)(m0 + mr) * 512 + kb * 8;
        f32x4 acc[2][4];
#pragma unroll
        for (int i = 0; i < 2; i++)
#pragma unroll
            for (int j = 0; j < 4; j++) acc[i][j] = zero4();
#pragma unroll 2
        for (int k0 = 0; k0 < 512; k0 += 32) {
            s16x8 bf[4], af[2];
#pragma unroll
            for (int nt = 0; nt < 4; ++nt) bf[nt] = *(const s16x8*)(bb + nt * 8192 + k0);
#pragma unroll
            for (int mt = 0; mt < 2; ++mt) af[mt] = *(const s16x8*)(ab + mt * 8192 + k0);
#pragma unroll
            for (int mt = 0; mt < 2; ++mt)
#pragma unroll
                for (int nt = 0; nt < 4; ++nt)
                    acc[mt][nt] = MFMA(af[mt], bf[nt], acc[mt][nt]);
        }
#pragma unroll
        for (int mt = 0; mt < 2; ++mt)
#pragma unroll
            for (int j = 0; j < 4; ++j) {
                float x0 = acc[mt][0][j] + bv[0];
                float x1 = acc[mt][1][j] + bv[1];
                float x2 = acc[mt][2][j] + bv[2];
                float x3 = acc[mt][3][j] + bv[3];
                float m = fmaxf(fmaxf(x0, x1), fmaxf(x2, x3));
                float s = __expf(x0 - m) + __expf(x1 - m) + __expf(x2 - m) + __expf(x3 - m);
#pragma unroll
                for (int off = 1; off <= 8; off <<= 1) {
                    float mo = __shfl_xor(m, off, 64), so = __shfl_xor(s, off, 64);
                    float nm = fmaxf(m, mo);
                    s = s * __expf(m - nm) + so * __expf(mo - nm);
                    m = nm;
                }
                if (mr == 0) {
                    int row = m0 + mt * 16 + kb * 4 + j;
                    pm[(long)(nb * 2 + wn) * 1280 + row] = m;
                    ps[(long)(nb * 2 + wn) * 1280 + row] = s;
                }
            }
    }
}

// ---------------- final LSE reduce + NLL accumulate ----------------
__global__ __launch_bounds__(64) void k_lseb(const float* __restrict__ pm,
                                             const float* __restrict__ ps,
                                             const us* __restrict__ obf_all,
                                             const float* __restrict__ o2pW,
                                             const float* __restrict__ o2pb,
                                             const int* __restrict__ y,
                                             float* __restrict__ out) {
    int r = blockIdx.x, lane = threadIdx.x;
    int t = r >> 6, b = r & 63;
    int tgt = y[(t + 1) * 64 + b];
    float m = -1e30f, s = 0.f;
    for (int p = lane; p < 500; p += 64) {
        float mi = pm[(long)p * 1280 + r], si = ps[(long)p * 1280 + r];
        float nm = fmaxf(m, mi);
        s = s * __expf(m - nm) + si * __expf(mi - nm);
        m = nm;
    }
#pragma unroll
    for (int off = 32; off; off >>= 1) {
        float mo = __shfl_xor(m, off, 64), so = __shfl_xor(s, off, 64);
        float nm = fmaxf(m, mo);
        s = s * __expf(m - nm) + so * __expf(mo - nm);
        m = nm;
    }
    float d = 0.f;
    const float* wr = o2pW + (long)tgt * 512;
#pragma unroll
    for (int k = 0; k < 8; ++k)
        d += b2f(obf_all[(long)r * 512 + lane + k * 64]) * wr[lane + k * 64];
#pragma unroll
    for (int off = 32; off; off >>= 1) d += __shfl_xor(d, off, 64);
    if (lane == 0 && tgt != 0)
        atomicAdd(out, (m + __logf(s)) - (d + o2pb[tgt]));
}

extern "C" void kernel_launch(void* const* d_in, const int* in_sizes, int n_in,
                              void* d_out, int out_size, void* d_ws, size_t ws_size,
                              hipStream_t stream) {
    const float* ctx     = (const float*)d_in[0];
    const int*   y       = (const int*)d_in[1];
    const float* embW    = (const float*)d_in[2];
    const float* att_c2c = (const float*)d_in[3];
    const float* att_h2c = (const float*)d_in[4];
    const float* mlp     = (const float*)d_in[5];
    const float* Wih     = (const float*)d_in[6];
    const float* bih     = (const float*)d_in[7];
    const float* Whh     = (const float*)d_in[8];
    const float* bhh     = (const float*)d_in[9];
    const float* h2oW    = (const float*)d_in[10];
    const float* h2ob    = (const float*)d_in[11];
    const float* octxW   = (const float*)d_in[12];
    const float* octxb   = (const float*)d_in[13];
    const float* o2pW    = (const float*)d_in[14];
    const float* o2pb    = (const float*)d_in[15];
    float* out = (float*)d_out;

    char* base = (char*)d_ws;
    us* ctxbf   = (us*)base; base += 25690112L;   // [s][b][c] bf16 (= GEMM A)
    us* cpbf    = (us*)base; base += 25690112L;   // [12544][1024]; pm/ps alias after loop
    us* c2cT    = (us*)base; base += 2097152L;
    us* attbf   = (us*)base; base += 2097152L;
    us* Wg      = (us*)base; base += 15728640L;
    us* h2obf   = (us*)base; base += 1048576L;
    us* octxbf  = (us*)base; base += 1048576L;
    us* o2pbf   = (us*)base; base += 32768000L;
    us* xc      = (us*)base; base += 6225920L;    // [19][64][2560]
    us* ht_all  = (us*)base; base += 2621440L;    // [20*64][1024], rows 0..63 = h0 = 0
    us* obf_all = (us*)base; base += 1310720L;    // [1280][512], rows 1216+ zero pad
    float* hf32   = (float*)base; base += 262144L;  // [64][1024]
    float* hpp    = (float*)base; base += 524288L;  // [2][64][1024]
    float* scb    = (float*)base; base += 50176L;   // [64][196]
    float* pm   = (float*)cpbf;                   // [500][1280] aliases cpbf (dead by then)
    float* ps   = pm + 640000L;

    (void)hipMemsetAsync(d_out, 0, sizeof(float), stream);
    (void)hipMemsetAsync(hf32, 0, 262144, stream);
    (void)hipMemsetAsync(ht_all, 0, 131072, stream);                // h0 rows
    (void)hipMemsetAsync(obf_all + 1216L * 512, 0, 65536, stream);  // pad rows
    (void)hipMemsetAsync(xc, 0, 6225920, stream);

    // prep
    k_yemb<<<TS_ * 64, 256, 0, stream>>>(y, embW, xc);
    k_tcvt<<<dim3(32, 32), dim3(32, 8), 0, stream>>>(att_c2c, c2cT);
    k_tcvt<<<dim3(32, 32), dim3(32, 8), 0, stream>>>(att_h2c, attbf);
    k_cvt<<<2048, 256, 0, stream>>>(ctx, ctxbf, 12845056L);
    k_cvt<<<512, 256, 0, stream>>>(h2oW, h2obf, 524288L);
    k_cvt<<<512, 256, 0, stream>>>(octxW, octxbf, 524288L);
    k_cvt<<<2048, 256, 0, stream>>>(o2pW, o2pbf, 16384000L);
    k_prepw<<<4096, 256, 0, stream>>>(Wih, Whh, Wg);
    k_gemm<<<392, 512, 0, stream>>>(ctxbf, c2cT, cpbf);

    // sequential recurrence: 4 kernels per step
    for (int t = 0; t < TS_; t++) {
        k_hproj<<<128, 256, 0, stream>>>(ht_all + (long)t * 65536, attbf, hpp);
        k_scores<<<3136, 256, 0, stream>>>(cpbf, hpp, mlp, scb);
        k_z<<<256, 512, 0, stream>>>(scb, ctxbf, xc, t);
        k_gruh2<<<256, 512, 0, stream>>>(xc, Wg, bih, bhh, hf32, ht_all, t);
    }

    // deferred output head, batched over all steps
    k_outb<<<dim3(19, 2), 256, 0, stream>>>(ht_all, xc, h2obf, h2ob, octxbf, octxb, obf_all);
    k_vocabb<<<250, 1024, 0, stream>>>(obf_all, o2pbf, o2pb, pm, ps);
    k_lseb<<<1216, 64, 0, stream>>>(pm, ps, obf_all, o2pW, o2pb, y, out);
}

// Round 10
// 1163.069 us; speedup vs baseline: 12.4349x; 1.0937x over previous
//
#include <hip/hip_runtime.h>
#include <math.h>

#define TS_ 19   // T-1 decode steps

typedef float f32x4 __attribute__((ext_vector_type(4)));
typedef short s16x8 __attribute__((ext_vector_type(8)));
typedef unsigned short us;
typedef unsigned char uc;

__device__ __forceinline__ float sigmoidf_(float x) { return 1.f / (1.f + __expf(-x)); }

__device__ __forceinline__ float fast_tanh(float x) {
    float ax = fabsf(x);
    float e = __expf(-2.f * ax);
    float r = (1.f - e) * __builtin_amdgcn_rcpf(1.f + e);
    return copysignf(r, x);
}

__device__ __forceinline__ us f2b(float x) {
    union { float f; unsigned u; } v; v.f = x;
    unsigned r = v.u + 0x7fffu + ((v.u >> 16) & 1u);
    return (us)(r >> 16);
}
__device__ __forceinline__ float b2f(us u) {
    union { unsigned u; float f; } v; v.u = ((unsigned)u) << 16; return v.f;
}
__device__ __forceinline__ uc f2e4m3(float x) {
    return (uc)(__builtin_amdgcn_cvt_pk_fp8_f32(x, 0.f, 0, false) & 0xff);
}

#define MFMA(a, b, c) __builtin_amdgcn_mfma_f32_16x16x32_bf16((a), (b), (c), 0, 0, 0)
#define MFMA8(a, b, c) __builtin_amdgcn_mfma_f32_16x16x32_fp8_fp8((a), (b), (c), 0, 0, 0)

__device__ __forceinline__ f32x4 zero4() { return (f32x4){0.f, 0.f, 0.f, 0.f}; }

__device__ __forceinline__ f32x4 wg16(const us* ap, const us* bp, int nk, f32x4 acc) {
#pragma unroll 4
    for (int k = 0; k < nk; k += 32)
        acc = MFMA(*(const s16x8*)(ap + k), *(const s16x8*)(bp + k), acc);
    return acc;
}

// ---------------- prep kernels ----------------
__global__ __launch_bounds__(256) void k_cvt(const float* __restrict__ in,
                                             us* __restrict__ out, long n) {
    long i = ((long)blockIdx.x * 256 + threadIdx.x) * 4;
    long stride = (long)gridDim.x * 1024;
    for (; i < n; i += stride) {
        float4 v = *(const float4*)(in + i);
        ushort4 o = { f2b(v.x), f2b(v.y), f2b(v.z), f2b(v.w) };
        *(ushort4*)(out + i) = o;
    }
}

__global__ __launch_bounds__(256) void k_cvt8(const float* __restrict__ in,
                                              uc* __restrict__ out, long n) {
    long i = ((long)blockIdx.x * 256 + threadIdx.x) * 8;
    long stride = (long)gridDim.x * 2048;
    for (; i < n; i += stride) {
        float4 v0 = *(const float4*)(in + i);
        float4 v1 = *(const float4*)(in + i + 4);
        int lo = __builtin_amdgcn_cvt_pk_fp8_f32(v0.x, v0.y, 0, false);
        lo = __builtin_amdgcn_cvt_pk_fp8_f32(v0.z, v0.w, lo, true);
        int hi = __builtin_amdgcn_cvt_pk_fp8_f32(v1.x, v1.y, 0, false);
        hi = __builtin_amdgcn_cvt_pk_fp8_f32(v1.z, v1.w, hi, true);
        int2 o = { lo, hi };
        *(int2*)(out + i) = o;
    }
}

__global__ void k_tcvt(const float* __restrict__ in, us* __restrict__ out) {
    __shared__ float tile[32][33];
    int bx = blockIdx.x * 32, by = blockIdx.y * 32;
    int x = threadIdx.x, y0 = threadIdx.y;
    for (int yy = y0; yy < 32; yy += 8) tile[yy][x] = in[(by + yy) * 1024 + bx + x];
    __syncthreads();
    for (int yy = y0; yy < 32; yy += 8) out[(bx + yy) * 1024 + by + x] = f2b(tile[x][yy]);
}

__global__ __launch_bounds__(256) void k_yemb(const int* __restrict__ y,
                                              const float* __restrict__ embW,
                                              us* __restrict__ xc) {
    int t = blockIdx.x >> 6, b = blockIdx.x & 63;
    int row = y[t * 64 + b];
    const float* src = embW + (long)row * 512;
    us* dst = xc + (long)(t * 64 + b) * 2560;
    for (int e = threadIdx.x; e < 512; e += 256) dst[e] = f2b(src[e]);
}

// packed gate weights: rows 0..2047 r/z (K=2560 = Wih|Whh); 2048..3071 i_n (K=1536);
// 3072..4095 h_n (K=1024)
__global__ __launch_bounds__(256) void k_prepw(const float* __restrict__ Wih,
                                               const float* __restrict__ Whh,
                                               us* __restrict__ Wg) {
    int n = blockIdx.x, tid = threadIdx.x;
    int cl = n >> 10;
    if (cl < 2) {
        long base = (long)n * 2560;
        const float* wi = Wih + (long)n * 1536;
        const float* wh = Whh + (long)n * 1024;
        for (int k = tid; k < 1536; k += 256) Wg[base + k] = f2b(wi[k]);
        for (int k = tid; k < 1024; k += 256) Wg[base + 1536 + k] = f2b(wh[k]);
    } else if (cl == 2) {
        long base = 5242880L + (long)(n - 2048) * 1536;
        const float* wi = Wih + (long)n * 1536;
        for (int k = tid; k < 1536; k += 256) Wg[base + k] = f2b(wi[k]);
    } else {
        long base = 6815744L + (long)(n - 3072) * 1024;
        const float* wh = Whh + (long)(n - 1024) * 1024;
        for (int k = tid; k < 1024; k += 256) Wg[base + k] = f2b(wh[k]);
    }
}

// ---------------- ctx_proj GEMM: A=ctxbf (bf16), BM=128 x BN=256, direct stream --
__global__ __launch_bounds__(512) void k_gemm(const us* __restrict__ A,
                                              const us* __restrict__ Bt,
                                              us* __restrict__ Cb) {
    int tid = threadIdx.x, lane = tid & 63, w = tid >> 6;
    int bm = blockIdx.x % 98, bn = blockIdx.x / 98;
    int mr = lane & 15, kb = lane >> 4;
    long m0 = (long)bm * 128 + (w >> 2) * 64;
    int n0 = bn * 256 + (w & 3) * 64;
    const us* ab = A + (m0 + mr) * 1024 + kb * 8;
    const us* bb = Bt + (long)(n0 + mr) * 1024 + kb * 8;

    f32x4 acc[4][4];
#pragma unroll
    for (int i = 0; i < 4; i++)
#pragma unroll
        for (int j = 0; j < 4; j++) acc[i][j] = zero4();

#pragma unroll 4
    for (int k0 = 0; k0 < 1024; k0 += 32) {
        s16x8 af[4], bf[4];
#pragma unroll
        for (int mt = 0; mt < 4; ++mt) af[mt] = *(const s16x8*)(ab + mt * 16384 + k0);
#pragma unroll
        for (int nt = 0; nt < 4; ++nt) bf[nt] = *(const s16x8*)(bb + nt * 16384 + k0);
#pragma unroll
        for (int mt = 0; mt < 4; ++mt)
#pragma unroll
            for (int nt = 0; nt < 4; ++nt)
                acc[mt][nt] = MFMA(af[mt], bf[nt], acc[mt][nt]);
    }
#pragma unroll
    for (int mt = 0; mt < 4; ++mt)
#pragma unroll
        for (int nt = 0; nt < 4; ++nt)
#pragma unroll
            for (int j = 0; j < 4; ++j)
                Cb[(m0 + mt * 16 + kb * 4 + j) * 1024 + n0 + nt * 16 + mr] =
                    f2b(acc[mt][nt][j]);
}

// ---------------- hproj parts: hpp[kc][b][n] = (h_t @ attT)_Khalf ----------------
__global__ __launch_bounds__(256) void k_hproj(const us* __restrict__ hcur,
                                               const us* __restrict__ attbf,
                                               float* __restrict__ hpp) {
    int tid = threadIdx.x, lane = tid & 63, w = tid >> 6;
    int vn0 = (blockIdx.x >> 1) * 16, kc = blockIdx.x & 1;
    int m0 = w * 16, mr = lane & 15, kb = lane >> 4;
    const us* ap = hcur + (long)(m0 + mr) * 1024 + kc * 512 + kb * 8;
    const us* bp = attbf + (long)(vn0 + mr) * 1024 + kc * 512 + kb * 8;
    f32x4 acc = wg16(ap, bp, 512, zero4());
#pragma unroll
    for (int j = 0; j < 4; ++j)
        hpp[(long)kc * 65536 + (long)(m0 + kb * 4 + j) * 1024 + vn0 + mr] = acc[j];
}

// ---------------- scores: 256 blocks (b x s-quarter), hp staged once ----------
__global__ __launch_bounds__(1024) void k_scores(const us* __restrict__ cpb,
                                                 const float* __restrict__ hpp,
                                                 const float* __restrict__ mlp,
                                                 float* __restrict__ scores) {
    __shared__ float hp[1024];
    __shared__ float ml[1024];
    int tid = threadIdx.x;
    int b = blockIdx.x >> 2, sq = blockIdx.x & 3;
    hp[tid] = hpp[(long)b * 1024 + tid] + hpp[65536 + (long)b * 1024 + tid];
    ml[tid] = mlp[tid];
    __syncthreads();
    int wv = tid >> 6, lane = tid & 63;
    int s0 = sq * 49;
    for (int s = s0 + wv; s < s0 + 49; s += 16) {
        const us* cp = cpb + (long)(s * 64 + b) * 1024 + lane * 16;
        s16x8 c0 = *(const s16x8*)cp;
        s16x8 c1 = *(const s16x8*)(cp + 8);
        int e0 = lane * 16;
        float acc = 0.f;
#pragma unroll
        for (int j = 0; j < 8; ++j)
            acc += fast_tanh(b2f((us)c0[j]) + hp[e0 + j]) * ml[e0 + j];
#pragma unroll
        for (int j = 0; j < 8; ++j)
            acc += fast_tanh(b2f((us)c1[j]) + hp[e0 + 8 + j]) * ml[e0 + 8 + j];
#pragma unroll
        for (int off = 32; off; off >>= 1) acc += __shfl_xor(acc, off, 64);
        if (lane == 0) scores[b * 196 + s] = acc;
    }
}

// ---------------- softmax + z -> xc z-slot; 512 thr, s-split halves ----------
__global__ __launch_bounds__(512) void k_z(const float* __restrict__ scores,
                                           const us* __restrict__ ctxbf,
                                           us* __restrict__ xc, int t) {
    __shared__ float red[512];
    __shared__ float als[196];
    __shared__ float zp[256];
    int tid = threadIdx.x, b = blockIdx.x >> 2, ch = blockIdx.x & 3;
    const float* sc = scores + b * 196;
    float lm = (tid < 196) ? sc[tid] : -1e30f;
    red[tid] = lm; __syncthreads();
    for (int st = 256; st; st >>= 1) { if (tid < st) red[tid] = fmaxf(red[tid], red[tid + st]); __syncthreads(); }
    float m = red[0]; __syncthreads();
    float ls = (tid < 196) ? __expf(sc[tid] - m) : 0.f;
    red[tid] = ls; __syncthreads();
    for (int st = 256; st; st >>= 1) { if (tid < st) red[tid] += red[tid + st]; __syncthreads(); }
    float inv = 1.f / red[0];
    if (tid < 196) als[tid] = ls * inv;
    __syncthreads();
    int c = ch * 256 + (tid & 255);
    int sh = tid >> 8;
    const us* cp = ctxbf + (long)b * 1024 + c;
    float a0 = 0.f;
    int sb = sh * 98;
    for (int s = sb; s < sb + 98; s += 2) {
        a0 += als[s] * b2f(cp[(long)s * 65536]) +
              als[s + 1] * b2f(cp[(long)(s + 1) * 65536]);
    }
    if (sh) zp[tid & 255] = a0;
    __syncthreads();
    if (!sh) {
        a0 += zp[tid & 255];
        xc[(long)(t * 64 + b) * 2560 + 512 + c] = f2b(a0);
    }
}

// ---------------- fused GRU: all 4 gates + update, one block per (j16, m16) ----
__global__ __launch_bounds__(512) void k_gruh2(us* __restrict__ xc,
                                               const us* __restrict__ Wg,
                                               const float* __restrict__ bih,
                                               const float* __restrict__ bhh,
                                               float* __restrict__ hf32,
                                               us* __restrict__ ht_all, int t) {
    __shared__ float lg[2048];   // [g*2+kh][m16][j16]
    int tid = threadIdx.x, lane = tid & 63, w = tid >> 6;
    int mr = lane & 15, kb = lane >> 4;
    int g = w >> 1, kh = w & 1;
    int mq = blockIdx.x & 3, jt = blockIdx.x >> 2;
    int m0 = mq * 16, j0 = jt * 16;
    const us* xr = xc + (long)t * 163840 + (long)(m0 + mr) * 2560;

    f32x4 acc = zero4();
    if (g == 0) {
        acc = wg16(xr + kh * 1280 + kb * 8,
                   Wg + (long)(j0 + mr) * 2560 + kh * 1280 + kb * 8, 1280, acc);
    } else if (g == 1) {
        acc = wg16(xr + kh * 1280 + kb * 8,
                   Wg + (long)(1024 + j0 + mr) * 2560 + kh * 1280 + kb * 8, 1280, acc);
    } else if (g == 2) {
        acc = wg16(xr + kh * 768 + kb * 8,
                   Wg + 5242880L + (long)(j0 + mr) * 1536 + kh * 768 + kb * 8, 768, acc);
    } else {
        acc = wg16(xr + 1536 + kh * 512 + kb * 8,
                   Wg + 6815744L + (long)(j0 + mr) * 1024 + kh * 512 + kb * 8, 512, acc);
    }
#pragma unroll
    for (int j = 0; j < 4; ++j)
        lg[(g * 2 + kh) * 256 + (kb * 4 + j) * 16 + mr] = acc[j];
    __syncthreads();

    if (tid < 256) {
        int ml = tid >> 4, jj = tid & 15;
        int b = m0 + ml, j = j0 + jj;
        float gr = lg[0 * 256 + ml * 16 + jj] + lg[1 * 256 + ml * 16 + jj];
        float gz = lg[2 * 256 + ml * 16 + jj] + lg[3 * 256 + ml * 16 + jj];
        float gi = lg[4 * 256 + ml * 16 + jj] + lg[5 * 256 + ml * 16 + jj];
        float gh = lg[6 * 256 + ml * 16 + jj] + lg[7 * 256 + ml * 16 + jj];
        float r  = sigmoidf_(gr + bih[j] + bhh[j]);
        float zz = sigmoidf_(gz + bih[1024 + j] + bhh[1024 + j]);
        float n  = fast_tanh(gi + bih[2048 + j] + r * (gh + bhh[2048 + j]));
        float h = (1.f - zz) * n + zz * hf32[b * 1024 + j];
        hf32[b * 1024 + j] = h;
        us hb = f2b(h);
        ht_all[(long)((t + 1) * 64 + b) * 1024 + j] = hb;
        if (t < TS_ - 1) xc[(long)((t + 1) * 64 + b) * 2560 + 1536 + j] = hb;
    }
}

// ---------------- batched output head: obf_all (bf16) + obf8 (fp8) -------------
__global__ __launch_bounds__(256) void k_outb(const us* __restrict__ ht_all,
                                              const us* __restrict__ xc,
                                              const us* __restrict__ h2obf,
                                              const float* __restrict__ h2ob,
                                              const us* __restrict__ octxbf,
                                              const float* __restrict__ octxb,
                                              us* __restrict__ obf_all,
                                              uc* __restrict__ obf8) {
    int tid = threadIdx.x, lane = tid & 63, w = tid >> 6;
    int mr = lane & 15, kb = lane >> 4;
    int m0 = blockIdx.x * 64;
    int n0 = blockIdx.y * 256 + w * 64;
    f32x4 a1[4][4], a2[4][4];
#pragma unroll
    for (int i = 0; i < 4; i++)
#pragma unroll
        for (int j = 0; j < 4; j++) { a1[i][j] = zero4(); a2[i][j] = zero4(); }

    for (int k0 = 0; k0 < 1024; k0 += 32) {
        s16x8 bf[4], af[4];
#pragma unroll
        for (int nt = 0; nt < 4; ++nt)
            bf[nt] = *(const s16x8*)(h2obf + (long)(n0 + nt * 16 + mr) * 1024 + k0 + kb * 8);
#pragma unroll
        for (int mt = 0; mt < 4; ++mt)
            af[mt] = *(const s16x8*)(ht_all + (long)(64 + m0 + mt * 16 + mr) * 1024 + k0 + kb * 8);
#pragma unroll
        for (int mt = 0; mt < 4; ++mt)
#pragma unroll
            for (int nt = 0; nt < 4; ++nt)
                a1[mt][nt] = MFMA(af[mt], bf[nt], a1[mt][nt]);
    }
    for (int k0 = 0; k0 < 1024; k0 += 32) {
        s16x8 bf[4], af[4];
#pragma unroll
        for (int nt = 0; nt < 4; ++nt)
            bf[nt] = *(const s16x8*)(octxbf + (long)(n0 + nt * 16 + mr) * 1024 + k0 + kb * 8);
#pragma unroll
        for (int mt = 0; mt < 4; ++mt)
            af[mt] = *(const s16x8*)(xc + (long)(m0 + mt * 16 + mr) * 2560 + 512 + k0 + kb * 8);
#pragma unroll
        for (int mt = 0; mt < 4; ++mt)
#pragma unroll
            for (int nt = 0; nt < 4; ++nt)
                a2[mt][nt] = MFMA(af[mt], bf[nt], a2[mt][nt]);
    }
#pragma unroll
    for (int mt = 0; mt < 4; ++mt)
#pragma unroll
        for (int nt = 0; nt < 4; ++nt) {
            int e = n0 + nt * 16 + mr;
            float b1 = h2ob[e], b2 = octxb[e];
#pragma unroll
            for (int j = 0; j < 4; ++j) {
                long row = m0 + mt * 16 + kb * 4 + j;
                float ye = b2f(xc[row * 2560 + e]);
                float val = fast_tanh(fast_tanh(a1[mt][nt][j] + b1) + ye + a2[mt][nt][j] + b2);
                obf_all[(row << 9) + e] = f2b(val);
                obf8[(row << 9) + e] = f2e4m3(val);
            }
        }
}

// ---------------- vocab GEMM (fp8) + partial LSE, XCD-co-located grid ----------
// 1280 blocks: x=bid&7 (XCD), idx=bid>>3; nb=x*32+idx/5 (0..255), mb=idx%5.
// All 5 m-blocks sharing a 128-row weight slice land on one XCD -> L2 reuse.
__global__ __launch_bounds__(512) void k_vocab8(const uc* __restrict__ obf8,
                                                const uc* __restrict__ o2p8,
                                                const float* __restrict__ o2pb,
                                                float* __restrict__ pm,
                                                float* __restrict__ ps) {
    int tid = threadIdx.x, lane = tid & 63, w = tid >> 6;
    int mr = lane & 15, kb = lane >> 4;
    int x = blockIdx.x & 7, idx = blockIdx.x >> 3;
    int nb = x * 32 + idx / 5, mb = idx % 5;
    int wm = w >> 1, wn = w & 1;
    int n0 = nb * 128 + wn * 64;
    int m0 = mb * 256 + wm * 64;
    const long* ab = (const long*)(obf8 + (long)(m0 + mr) * 512 + kb * 8);
    const long* bb = (const long*)(o2p8 + (long)(n0 + mr) * 512 + kb * 8);
    f32x4 acc[4][4];
#pragma unroll
    for (int i = 0; i < 4; i++)
#pragma unroll
        for (int j = 0; j < 4; j++) acc[i][j] = zero4();

#pragma unroll 4
    for (int kq = 0; kq < 64; kq += 4) {   // 8 fp8/long; 4 longs = K 32 per MFMA
        long af[4], bf[4];
#pragma unroll
        for (int nt = 0; nt < 4; ++nt) bf[nt] = bb[nt * 1024 + kq];
#pragma unroll
        for (int mt = 0; mt < 4; ++mt) af[mt] = ab[mt * 1024 + kq];
#pragma unroll
        for (int mt = 0; mt < 4; ++mt)
#pragma unroll
            for (int nt = 0; nt < 4; ++nt)
                acc[mt][nt] = MFMA8(af[mt], bf[nt], acc[mt][nt]);
    }
    float bv[4];
#pragma unroll
    for (int nt = 0; nt < 4; ++nt) {
        int vn = n0 + nt * 16 + mr;
        bv[nt] = (vn < 32000) ? o2pb[vn] : -1e30f;
    }
#pragma unroll
    for (int mt = 0; mt < 4; ++mt)
#pragma unroll
        for (int j = 0; j < 4; ++j) {
            float x0 = acc[mt][0][j] + bv[0];
            float x1 = acc[mt][1][j] + bv[1];
            float x2 = acc[mt][2][j] + bv[2];
            float x3 = acc[mt][3][j] + bv[3];
            float m = fmaxf(fmaxf(x0, x1), fmaxf(x2, x3));
            float s = __expf(x0 - m) + __expf(x1 - m) + __expf(x2 - m) + __expf(x3 - m);
#pragma unroll
            for (int off = 1; off <= 8; off <<= 1) {
                float mo = __shfl_xor(m, off, 64), so = __shfl_xor(s, off, 64);
                float nm = fmaxf(m, mo);
                s = s * __expf(m - nm) + so * __expf(mo - nm);
                m = nm;
            }
            if (mr == 0) {
                int row = m0 + mt * 16 + kb * 4 + j;
                pm[(long)(nb * 2 + wn) * 1280 + row] = m;
                ps[(long)(nb * 2 + wn) * 1280 + row] = s;
            }
        }
}

// ---------------- final LSE reduce + NLL accumulate ----------------
__global__ __launch_bounds__(64) void k_lseb(const float* __restrict__ pm,
                                             const float* __restrict__ ps,
                                             const us* __restrict__ obf_all,
                                             const float* __restrict__ o2pW,
                                             const float* __restrict__ o2pb,
                                             const int* __restrict__ y,
                                             float* __restrict__ out) {
    int r = blockIdx.x, lane = threadIdx.x;
    int t = r >> 6, b = r & 63;
    int tgt = y[(t + 1) * 64 + b];
    float m = -1e30f, s = 0.f;
    for (int p = lane; p < 512; p += 64) {
        float mi = pm[(long)p * 1280 + r], si = ps[(long)p * 1280 + r];
        float nm = fmaxf(m, mi);
        s = s * __expf(m - nm) + si * __expf(mi - nm);
        m = nm;
    }
#pragma unroll
    for (int off = 32; off; off >>= 1) {
        float mo = __shfl_xor(m, off, 64), so = __shfl_xor(s, off, 64);
        float nm = fmaxf(m, mo);
        s = s * __expf(m - nm) + so * __expf(mo - nm);
        m = nm;
    }
    float d = 0.f;
    const float* wr = o2pW + (long)tgt * 512;
#pragma unroll
    for (int k = 0; k < 8; ++k)
        d += b2f(obf_all[(long)r * 512 + lane + k * 64]) * wr[lane + k * 64];
#pragma unroll
    for (int off = 32; off; off >>= 1) d += __shfl_xor(d, off, 64);
    if (lane == 0 && tgt != 0)
        atomicAdd(out, (m + __logf(s)) - (d + o2pb[tgt]));
}

extern "C" void kernel_launch(void* const* d_in, const int* in_sizes, int n_in,
                              void* d_out, int out_size, void* d_ws, size_t ws_size,
                              hipStream_t stream) {
    const float* ctx     = (const float*)d_in[0];
    const int*   y       = (const int*)d_in[1];
    const float* embW    = (const float*)d_in[2];
    const float* att_c2c = (const float*)d_in[3];
    const float* att_h2c = (const float*)d_in[4];
    const float* mlp     = (const float*)d_in[5];
    const float* Wih     = (const float*)d_in[6];
    const float* bih     = (const float*)d_in[7];
    const float* Whh     = (const float*)d_in[8];
    const float* bhh     = (const float*)d_in[9];
    const float* h2oW    = (const float*)d_in[10];
    const float* h2ob    = (const float*)d_in[11];
    const float* octxW   = (const float*)d_in[12];
    const float* octxb   = (const float*)d_in[13];
    const float* o2pW    = (const float*)d_in[14];
    const float* o2pb    = (const float*)d_in[15];
    float* out = (float*)d_out;

    char* base = (char*)d_ws;
    us* ctxbf   = (us*)base; base += 25690112L;   // [s][b][c] bf16 (= GEMM A)
    us* cpbf    = (us*)base; base += 25690112L;   // [12544][1024]; pm/ps alias after loop
    us* c2cT    = (us*)base; base += 2097152L;
    us* attbf   = (us*)base; base += 2097152L;
    us* Wg      = (us*)base; base += 15728640L;
    us* h2obf   = (us*)base; base += 1048576L;
    us* octxbf  = (us*)base; base += 1048576L;
    uc* o2p8    = (uc*)base; base += 16777216L;   // [32768][512] fp8, rows 32000+ zero
    us* xc      = (us*)base; base += 6225920L;    // [19][64][2560]
    us* ht_all  = (us*)base; base += 2621440L;    // [20*64][1024], rows 0..63 = h0 = 0
    us* obf_all = (us*)base; base += 1310720L;    // [1280][512] bf16, rows 1216+ pad
    uc* obf8    = (uc*)base; base += 655360L;     // [1280][512] fp8
    float* hf32   = (float*)base; base += 262144L;  // [64][1024]
    float* hpp    = (float*)base; base += 524288L;  // [2][64][1024]
    float* scb    = (float*)base; base += 50176L;   // [64][196]
    float* pm   = (float*)cpbf;                   // [512][1280] aliases cpbf (dead by then)
    float* ps   = pm + 655360L;

    (void)hipMemsetAsync(d_out, 0, sizeof(float), stream);
    (void)hipMemsetAsync(hf32, 0, 262144, stream);
    (void)hipMemsetAsync(ht_all, 0, 131072, stream);                 // h0 rows
    (void)hipMemsetAsync(obf_all + 1216L * 512, 0, 65536, stream);   // bf16 pad rows
    (void)hipMemsetAsync(obf8 + 1216L * 512, 0, 32768, stream);      // fp8 pad rows
    (void)hipMemsetAsync(o2p8 + 16384000L, 0, 393216, stream);       // weight pad rows
    (void)hipMemsetAsync(xc, 0, 6225920, stream);

    // prep
    k_yemb<<<TS_ * 64, 256, 0, stream>>>(y, embW, xc);
    k_tcvt<<<dim3(32, 32), dim3(32, 8), 0, stream>>>(att_c2c, c2cT);
    k_tcvt<<<dim3(32, 32), dim3(32, 8), 0, stream>>>(att_h2c, attbf);
    k_cvt<<<2048, 256, 0, stream>>>(ctx, ctxbf, 12845056L);
    k_cvt<<<512, 256, 0, stream>>>(h2oW, h2obf, 524288L);
    k_cvt<<<512, 256, 0, stream>>>(octxW, octxbf, 524288L);
    k_cvt8<<<2048, 256, 0, stream>>>(o2pW, o2p8, 16384000L);
    k_prepw<<<4096, 256, 0, stream>>>(Wih, Whh, Wg);
    k_gemm<<<392, 512, 0, stream>>>(ctxbf, c2cT, cpbf);

    // sequential recurrence: 4 kernels per step
    for (int t = 0; t < TS_; t++) {
        k_hproj<<<128, 256, 0, stream>>>(ht_all + (long)t * 65536, attbf, hpp);
        k_scores<<<256, 1024, 0, stream>>>(cpbf, hpp, mlp, scb);
        k_z<<<256, 512, 0, stream>>>(scb, ctxbf, xc, t);
        k_gruh2<<<256, 512, 0, stream>>>(xc, Wg, bih, bhh, hf32, ht_all, t);
    }

    // deferred output head, batched over all steps
    k_outb<<<dim3(19, 2), 256, 0, stream>>>(ht_all, xc, h2obf, h2ob, octxbf, octxb,
                                            obf_all, obf8);
    k_vocab8<<<1280, 512, 0, stream>>>(obf8, o2p8, o2pb, pm, ps);
    k_lseb<<<1216, 64, 0, stream>>>(pm, ps, obf_all, o2pW, o2pb, y, out);
}

// Round 11
// 975.381 us; speedup vs baseline: 14.8277x; 1.1924x over previous
//
#include <hip/hip_runtime.h>
#include <math.h>

#define TS_ 19   // T-1 decode steps

typedef float f32x4 __attribute__((ext_vector_type(4)));
typedef short s16x8 __attribute__((ext_vector_type(8)));
typedef unsigned short us;
typedef unsigned char uc;

__device__ __forceinline__ float sigmoidf_(float x) { return 1.f / (1.f + __expf(-x)); }

__device__ __forceinline__ float fast_tanh(float x) {
    float ax = fabsf(x);
    float e = __expf(-2.f * ax);
    float r = (1.f - e) * __builtin_amdgcn_rcpf(1.f + e);
    return copysignf(r, x);
}

__device__ __forceinline__ us f2b(float x) {
    union { float f; unsigned u; } v; v.f = x;
    unsigned r = v.u + 0x7fffu + ((v.u >> 16) & 1u);
    return (us)(r >> 16);
}
__device__ __forceinline__ float b2f(us u) {
    union { unsigned u; float f; } v; v.u = ((unsigned)u) << 16; return v.f;
}
__device__ __forceinline__ uc f2e4m3(float x) {
    return (uc)(__builtin_amdgcn_cvt_pk_fp8_f32(x, 0.f, 0, false) & 0xff);
}

#define MFMA(a, b, c) __builtin_amdgcn_mfma_f32_16x16x32_bf16((a), (b), (c), 0, 0, 0)
#define MFMA8(a, b, c) __builtin_amdgcn_mfma_f32_16x16x32_fp8_fp8((a), (b), (c), 0, 0, 0)

__device__ __forceinline__ f32x4 zero4() { return (f32x4){0.f, 0.f, 0.f, 0.f}; }

__device__ __forceinline__ f32x4 wg16(const us* ap, const us* bp, int nk, f32x4 acc) {
#pragma unroll 4
    for (int k = 0; k < nk; k += 32)
        acc = MFMA(*(const s16x8*)(ap + k), *(const s16x8*)(bp + k), acc);
    return acc;
}

// async global -> LDS, 16B per lane; dest = wave-uniform base + lane*16
__device__ __forceinline__ void gload_lds16(const void* g, void* l) {
    __builtin_amdgcn_global_load_lds(
        (const __attribute__((address_space(1))) unsigned int*)g,
        (__attribute__((address_space(3))) unsigned int*)l, 16, 0, 0);
}

// ---------------- prep kernels ----------------
__global__ __launch_bounds__(256) void k_cvt(const float* __restrict__ in,
                                             us* __restrict__ out, long n) {
    long i = ((long)blockIdx.x * 256 + threadIdx.x) * 4;
    long stride = (long)gridDim.x * 1024;
    for (; i < n; i += stride) {
        float4 v = *(const float4*)(in + i);
        ushort4 o = { f2b(v.x), f2b(v.y), f2b(v.z), f2b(v.w) };
        *(ushort4*)(out + i) = o;
    }
}

__global__ __launch_bounds__(256) void k_cvt8(const float* __restrict__ in,
                                              uc* __restrict__ out, long n) {
    long i = ((long)blockIdx.x * 256 + threadIdx.x) * 8;
    long stride = (long)gridDim.x * 2048;
    for (; i < n; i += stride) {
        float4 v0 = *(const float4*)(in + i);
        float4 v1 = *(const float4*)(in + i + 4);
        int lo = __builtin_amdgcn_cvt_pk_fp8_f32(v0.x, v0.y, 0, false);
        lo = __builtin_amdgcn_cvt_pk_fp8_f32(v0.z, v0.w, lo, true);
        int hi = __builtin_amdgcn_cvt_pk_fp8_f32(v1.x, v1.y, 0, false);
        hi = __builtin_amdgcn_cvt_pk_fp8_f32(v1.z, v1.w, hi, true);
        int2 o = { lo, hi };
        *(int2*)(out + i) = o;
    }
}

__global__ void k_tcvt(const float* __restrict__ in, us* __restrict__ out) {
    __shared__ float tile[32][33];
    int bx = blockIdx.x * 32, by = blockIdx.y * 32;
    int x = threadIdx.x, y0 = threadIdx.y;
    for (int yy = y0; yy < 32; yy += 8) tile[yy][x] = in[(by + yy) * 1024 + bx + x];
    __syncthreads();
    for (int yy = y0; yy < 32; yy += 8) out[(bx + yy) * 1024 + by + x] = f2b(tile[x][yy]);
}

__global__ __launch_bounds__(256) void k_yemb(const int* __restrict__ y,
                                              const float* __restrict__ embW,
                                              us* __restrict__ xc) {
    int t = blockIdx.x >> 6, b = blockIdx.x & 63;
    int row = y[t * 64 + b];
    const float* src = embW + (long)row * 512;
    us* dst = xc + (long)(t * 64 + b) * 2560;
    for (int e = threadIdx.x; e < 512; e += 256) dst[e] = f2b(src[e]);
}

// packed gate weights: rows 0..2047 r/z (K=2560 = Wih|Whh); 2048..3071 i_n (K=1536);
// 3072..4095 h_n (K=1024)
__global__ __launch_bounds__(256) void k_prepw(const float* __restrict__ Wih,
                                               const float* __restrict__ Whh,
                                               us* __restrict__ Wg) {
    int n = blockIdx.x, tid = threadIdx.x;
    int cl = n >> 10;
    if (cl < 2) {
        long base = (long)n * 2560;
        const float* wi = Wih + (long)n * 1536;
        const float* wh = Whh + (long)n * 1024;
        for (int k = tid; k < 1536; k += 256) Wg[base + k] = f2b(wi[k]);
        for (int k = tid; k < 1024; k += 256) Wg[base + 1536 + k] = f2b(wh[k]);
    } else if (cl == 2) {
        long base = 5242880L + (long)(n - 2048) * 1536;
        const float* wi = Wih + (long)n * 1536;
        for (int k = tid; k < 1536; k += 256) Wg[base + k] = f2b(wi[k]);
    } else {
        long base = 6815744L + (long)(n - 3072) * 1024;
        const float* wh = Whh + (long)(n - 1024) * 1024;
        for (int k = tid; k < 1024; k += 256) Wg[base + k] = f2b(wh[k]);
    }
}

// ---------------- ctx_proj GEMM (m97 structure): 128x128 tile, BK=64 ----------
// A=ctxbf [12544][1024] bf16, Bt=c2cT [1024][1024] bf16 ([n][k]), out bf16.
// LDS linear rows of 128B; XOR-swizzle ((row&7)<<4) folded into global source.
__global__ __launch_bounds__(256) void k_gemm(const us* __restrict__ A,
                                              const us* __restrict__ Bt,
                                              us* __restrict__ Cb) {
    __shared__ us As[8192], Bs[8192];   // 128 rows x 64 elems each
    int tid = threadIdx.x, lane = tid & 63, w = tid >> 6;
    int mr = lane & 15, kb = lane >> 4;
    int bm = blockIdx.x % 98, bn = blockIdx.x / 98;
    long m0 = (long)bm * 128;
    int n0 = bn * 128;
    int wr = w >> 1, wc = w & 1;
    int srow = w * 32 + (lane >> 3);
    int ib = (lane & 7) * 16;

    f32x4 acc[4][4];
#pragma unroll
    for (int i = 0; i < 4; i++)
#pragma unroll
        for (int j = 0; j < 4; j++) acc[i][j] = zero4();

    for (int kt = 0; kt < 16; ++kt) {
        int k0 = kt * 64;
        __syncthreads();
#pragma unroll
        for (int c = 0; c < 4; ++c) {
            int r = srow + c * 8;
            int sw = (ib ^ ((r & 7) << 4)) >> 1;   // element offset within row
            gload_lds16(A + (m0 + r) * 1024 + k0 + sw, &As[w * 2048 + c * 512]);
            gload_lds16(Bt + (long)(n0 + r) * 1024 + k0 + sw, &Bs[w * 2048 + c * 512]);
        }
        __syncthreads();
#pragma unroll
        for (int ks = 0; ks < 2; ++ks) {
            s16x8 af[4], bf[4];
#pragma unroll
            for (int mt = 0; mt < 4; ++mt) {
                int r = wr * 64 + mt * 16 + mr;
                af[mt] = *(const s16x8*)&As[(r * 128 + ((ks * 64 + kb * 16) ^ ((r & 7) << 4))) >> 1];
            }
#pragma unroll
            for (int nt = 0; nt < 4; ++nt) {
                int r = wc * 64 + nt * 16 + mr;
                bf[nt] = *(const s16x8*)&Bs[(r * 128 + ((ks * 64 + kb * 16) ^ ((r & 7) << 4))) >> 1];
            }
#pragma unroll
            for (int mt = 0; mt < 4; ++mt)
#pragma unroll
                for (int nt = 0; nt < 4; ++nt)
                    acc[mt][nt] = MFMA(af[mt], bf[nt], acc[mt][nt]);
        }
    }
#pragma unroll
    for (int mt = 0; mt < 4; ++mt)
#pragma unroll
        for (int nt = 0; nt < 4; ++nt)
#pragma unroll
            for (int j = 0; j < 4; ++j)
                Cb[(m0 + wr * 64 + mt * 16 + kb * 4 + j) * 1024 +
                   n0 + wc * 64 + nt * 16 + mr] = f2b(acc[mt][nt][j]);
}

// ---------------- hproj parts: hpp[kc][b][n] = (h_t @ attT)_Khalf ----------------
__global__ __launch_bounds__(256) void k_hproj(const us* __restrict__ hcur,
                                               const us* __restrict__ attbf,
                                               float* __restrict__ hpp) {
    int tid = threadIdx.x, lane = tid & 63, w = tid >> 6;
    int vn0 = (blockIdx.x >> 1) * 16, kc = blockIdx.x & 1;
    int m0 = w * 16, mr = lane & 15, kb = lane >> 4;
    const us* ap = hcur + (long)(m0 + mr) * 1024 + kc * 512 + kb * 8;
    const us* bp = attbf + (long)(vn0 + mr) * 1024 + kc * 512 + kb * 8;
    f32x4 acc = wg16(ap, bp, 512, zero4());
#pragma unroll
    for (int j = 0; j < 4; ++j)
        hpp[(long)kc * 65536 + (long)(m0 + kb * 4 + j) * 1024 + vn0 + mr] = acc[j];
}

// ---------------- scores: 256 blocks (b x s-quarter), hp staged once ----------
__global__ __launch_bounds__(1024) void k_scores(const us* __restrict__ cpb,
                                                 const float* __restrict__ hpp,
                                                 const float* __restrict__ mlp,
                                                 float* __restrict__ scores) {
    __shared__ float hp[1024];
    __shared__ float ml[1024];
    int tid = threadIdx.x;
    int b = blockIdx.x >> 2, sq = blockIdx.x & 3;
    hp[tid] = hpp[(long)b * 1024 + tid] + hpp[65536 + (long)b * 1024 + tid];
    ml[tid] = mlp[tid];
    __syncthreads();
    int wv = tid >> 6, lane = tid & 63;
    int s0 = sq * 49;
    for (int s = s0 + wv; s < s0 + 49; s += 16) {
        const us* cp = cpb + (long)(s * 64 + b) * 1024 + lane * 16;
        s16x8 c0 = *(const s16x8*)cp;
        s16x8 c1 = *(const s16x8*)(cp + 8);
        int e0 = lane * 16;
        float acc = 0.f;
#pragma unroll
        for (int j = 0; j < 8; ++j)
            acc += fast_tanh(b2f((us)c0[j]) + hp[e0 + j]) * ml[e0 + j];
#pragma unroll
        for (int j = 0; j < 8; ++j)
            acc += fast_tanh(b2f((us)c1[j]) + hp[e0 + 8 + j]) * ml[e0 + 8 + j];
#pragma unroll
        for (int off = 32; off; off >>= 1) acc += __shfl_xor(acc, off, 64);
        if (lane == 0) scores[b * 196 + s] = acc;
    }
}

// ---------------- softmax + z -> xc z-slot; 512 thr, s-split halves ----------
__global__ __launch_bounds__(512) void k_z(const float* __restrict__ scores,
                                           const us* __restrict__ ctxbf,
                                           us* __restrict__ xc, int t) {
    __shared__ float red[512];
    __shared__ float als[196];
    __shared__ float zp[256];
    int tid = threadIdx.x, b = blockIdx.x >> 2, ch = blockIdx.x & 3;
    const float* sc = scores + b * 196;
    float lm = (tid < 196) ? sc[tid] : -1e30f;
    red[tid] = lm; __syncthreads();
    for (int st = 256; st; st >>= 1) { if (tid < st) red[tid] = fmaxf(red[tid], red[tid + st]); __syncthreads(); }
    float m = red[0]; __syncthreads();
    float ls = (tid < 196) ? __expf(sc[tid] - m) : 0.f;
    red[tid] = ls; __syncthreads();
    for (int st = 256; st; st >>= 1) { if (tid < st) red[tid] += red[tid + st]; __syncthreads(); }
    float inv = 1.f / red[0];
    if (tid < 196) als[tid] = ls * inv;
    __syncthreads();
    int c = ch * 256 + (tid & 255);
    int sh = tid >> 8;
    const us* cp = ctxbf + (long)b * 1024 + c;
    float a0 = 0.f;
    int sb = sh * 98;
    for (int s = sb; s < sb + 98; s += 2) {
        a0 += als[s] * b2f(cp[(long)s * 65536]) +
              als[s + 1] * b2f(cp[(long)(s + 1) * 65536]);
    }
    if (sh) zp[tid & 255] = a0;
    __syncthreads();
    if (!sh) {
        a0 += zp[tid & 255];
        xc[(long)(t * 64 + b) * 2560 + 512 + c] = f2b(a0);
    }
}

// ---------------- fused GRU: all 4 gates + update, one block per (j16, m16) ----
__global__ __launch_bounds__(512) void k_gruh2(us* __restrict__ xc,
                                               const us* __restrict__ Wg,
                                               const float* __restrict__ bih,
                                               const float* __restrict__ bhh,
                                               float* __restrict__ hf32,
                                               us* __restrict__ ht_all, int t) {
    __shared__ float lg[2048];   // [g*2+kh][m16][j16]
    int tid = threadIdx.x, lane = tid & 63, w = tid >> 6;
    int mr = lane & 15, kb = lane >> 4;
    int g = w >> 1, kh = w & 1;
    int mq = blockIdx.x & 3, jt = blockIdx.x >> 2;
    int m0 = mq * 16, j0 = jt * 16;
    const us* xr = xc + (long)t * 163840 + (long)(m0 + mr) * 2560;

    f32x4 acc = zero4();
    if (g == 0) {
        acc = wg16(xr + kh * 1280 + kb * 8,
                   Wg + (long)(j0 + mr) * 2560 + kh * 1280 + kb * 8, 1280, acc);
    } else if (g == 1) {
        acc = wg16(xr + kh * 1280 + kb * 8,
                   Wg + (long)(1024 + j0 + mr) * 2560 + kh * 1280 + kb * 8, 1280, acc);
    } else if (g == 2) {
        acc = wg16(xr + kh * 768 + kb * 8,
                   Wg + 5242880L + (long)(j0 + mr) * 1536 + kh * 768 + kb * 8, 768, acc);
    } else {
        acc = wg16(xr + 1536 + kh * 512 + kb * 8,
                   Wg + 6815744L + (long)(j0 + mr) * 1024 + kh * 512 + kb * 8, 512, acc);
    }
#pragma unroll
    for (int j = 0; j < 4; ++j)
        lg[(g * 2 + kh) * 256 + (kb * 4 + j) * 16 + mr] = acc[j];
    __syncthreads();

    if (tid < 256) {
        int ml = tid >> 4, jj = tid & 15;
        int b = m0 + ml, j = j0 + jj;
        float gr = lg[0 * 256 + ml * 16 + jj] + lg[1 * 256 + ml * 16 + jj];
        float gz = lg[2 * 256 + ml * 16 + jj] + lg[3 * 256 + ml * 16 + jj];
        float gi = lg[4 * 256 + ml * 16 + jj] + lg[5 * 256 + ml * 16 + jj];
        float gh = lg[6 * 256 + ml * 16 + jj] + lg[7 * 256 + ml * 16 + jj];
        float r  = sigmoidf_(gr + bih[j] + bhh[j]);
        float zz = sigmoidf_(gz + bih[1024 + j] + bhh[1024 + j]);
        float n  = fast_tanh(gi + bih[2048 + j] + r * (gh + bhh[2048 + j]));
        float h = (1.f - zz) * n + zz * hf32[b * 1024 + j];
        hf32[b * 1024 + j] = h;
        us hb = f2b(h);
        ht_all[(long)((t + 1) * 64 + b) * 1024 + j] = hb;
        if (t < TS_ - 1) xc[(long)((t + 1) * 64 + b) * 2560 + 1536 + j] = hb;
    }
}

// ---------------- batched output head: obf_all (bf16) + obf8 (fp8) -------------
__global__ __launch_bounds__(256) void k_outb(const us* __restrict__ ht_all,
                                              const us* __restrict__ xc,
                                              const us* __restrict__ h2obf,
                                              const float* __restrict__ h2ob,
                                              const us* __restrict__ octxbf,
                                              const float* __restrict__ octxb,
                                              us* __restrict__ obf_all,
                                              uc* __restrict__ obf8) {
    int tid = threadIdx.x, lane = tid & 63, w = tid >> 6;
    int mr = lane & 15, kb = lane >> 4;
    int m0 = blockIdx.x * 64;
    int n0 = blockIdx.y * 256 + w * 64;
    f32x4 a1[4][4], a2[4][4];
#pragma unroll
    for (int i = 0; i < 4; i++)
#pragma unroll
        for (int j = 0; j < 4; j++) { a1[i][j] = zero4(); a2[i][j] = zero4(); }

    for (int k0 = 0; k0 < 1024; k0 += 32) {
        s16x8 bf[4], af[4];
#pragma unroll
        for (int nt = 0; nt < 4; ++nt)
            bf[nt] = *(const s16x8*)(h2obf + (long)(n0 + nt * 16 + mr) * 1024 + k0 + kb * 8);
#pragma unroll
        for (int mt = 0; mt < 4; ++mt)
            af[mt] = *(const s16x8*)(ht_all + (long)(64 + m0 + mt * 16 + mr) * 1024 + k0 + kb * 8);
#pragma unroll
        for (int mt = 0; mt < 4; ++mt)
#pragma unroll
            for (int nt = 0; nt < 4; ++nt)
                a1[mt][nt] = MFMA(af[mt], bf[nt], a1[mt][nt]);
    }
    for (int k0 = 0; k0 < 1024; k0 += 32) {
        s16x8 bf[4], af[4];
#pragma unroll
        for (int nt = 0; nt < 4; ++nt)
            bf[nt] = *(const s16x8*)(octxbf + (long)(n0 + nt * 16 + mr) * 1024 + k0 + kb * 8);
#pragma unroll
        for (int mt = 0; mt < 4; ++mt)
            af[mt] = *(const s16x8*)(xc + (long)(m0 + mt * 16 + mr) * 2560 + 512 + k0 + kb * 8);
#pragma unroll
        for (int mt = 0; mt < 4; ++mt)
#pragma unroll
            for (int nt = 0; nt < 4; ++nt)
                a2[mt][nt] = MFMA(af[mt], bf[nt], a2[mt][nt]);
    }
#pragma unroll
    for (int mt = 0; mt < 4; ++mt)
#pragma unroll
        for (int nt = 0; nt < 4; ++nt) {
            int e = n0 + nt * 16 + mr;
            float b1 = h2ob[e], b2 = octxb[e];
#pragma unroll
            for (int j = 0; j < 4; ++j) {
                long row = m0 + mt * 16 + kb * 4 + j;
                float ye = b2f(xc[row * 2560 + e]);
                float val = fast_tanh(fast_tanh(a1[mt][nt][j] + b1) + ye + a2[mt][nt][j] + b2);
                obf_all[(row << 9) + e] = f2b(val);
                obf8[(row << 9) + e] = f2e4m3(val);
            }
        }
}

// ---------------- vocab GEMM (fp8, m97 structure) + partial LSE ----------------
// 128x128 tile, BK=64. Grid 2560 = 8 XCD x 32 nb x 10 mb (m-blocks sharing a
// weight slice co-located per XCD). LDS rows 64B, swizzle ((row&6)<<3).
__global__ __launch_bounds__(256) void k_vocab8(const uc* __restrict__ obf8,
                                                const uc* __restrict__ o2p8,
                                                const float* __restrict__ o2pb,
                                                float* __restrict__ pm,
                                                float* __restrict__ ps) {
    __shared__ uc As[8192], Bs[8192];   // 128 rows x 64 B each
    int tid = threadIdx.x, lane = tid & 63, w = tid >> 6;
    int mr = lane & 15, kb = lane >> 4;
    int xq = blockIdx.x & 7, idx = blockIdx.x >> 3;
    int nb = xq * 32 + idx / 10, mb = idx % 10;
    int m0 = mb * 128, n0 = nb * 128;
    int wr = w >> 1, wc = w & 1;
    int srow = w * 32 + (lane >> 2);
    int ib = (lane & 3) * 16;

    f32x4 acc[4][4];
#pragma unroll
    for (int i = 0; i < 4; i++)
#pragma unroll
        for (int j = 0; j < 4; j++) acc[i][j] = zero4();

    for (int kt = 0; kt < 8; ++kt) {
        int k0 = kt * 64;
        __syncthreads();
#pragma unroll
        for (int c = 0; c < 2; ++c) {
            int r = srow + c * 16;
            int sw = ib ^ ((r & 6) << 3);
            gload_lds16(obf8 + (long)(m0 + r) * 512 + k0 + sw, &As[w * 2048 + c * 1024]);
            gload_lds16(o2p8 + (long)(n0 + r) * 512 + k0 + sw, &Bs[w * 2048 + c * 1024]);
        }
        __syncthreads();
#pragma unroll
        for (int ks = 0; ks < 2; ++ks) {
            long af[4], bf[4];
#pragma unroll
            for (int mt = 0; mt < 4; ++mt) {
                int r = wr * 64 + mt * 16 + mr;
                af[mt] = *(const long*)&As[r * 64 + ((ks * 32 + kb * 8) ^ ((r & 6) << 3))];
            }
#pragma unroll
            for (int nt = 0; nt < 4; ++nt) {
                int r = wc * 64 + nt * 16 + mr;
                bf[nt] = *(const long*)&Bs[r * 64 + ((ks * 32 + kb * 8) ^ ((r & 6) << 3))];
            }
#pragma unroll
            for (int mt = 0; mt < 4; ++mt)
#pragma unroll
                for (int nt = 0; nt < 4; ++nt)
                    acc[mt][nt] = MFMA8(af[mt], bf[nt], acc[mt][nt]);
        }
    }

    int n0w = n0 + wc * 64;
    float bv[4];
#pragma unroll
    for (int nt = 0; nt < 4; ++nt) {
        int vn = n0w + nt * 16 + mr;
        bv[nt] = (vn < 32000) ? o2pb[vn] : -1e30f;
    }
#pragma unroll
    for (int mt = 0; mt < 4; ++mt)
#pragma unroll
        for (int j = 0; j < 4; ++j) {
            float x0 = acc[mt][0][j] + bv[0];
            float x1 = acc[mt][1][j] + bv[1];
            float x2 = acc[mt][2][j] + bv[2];
            float x3 = acc[mt][3][j] + bv[3];
            float m = fmaxf(fmaxf(x0, x1), fmaxf(x2, x3));
            float s = __expf(x0 - m) + __expf(x1 - m) + __expf(x2 - m) + __expf(x3 - m);
#pragma unroll
            for (int off = 1; off <= 8; off <<= 1) {
                float mo = __shfl_xor(m, off, 64), so = __shfl_xor(s, off, 64);
                float nm = fmaxf(m, mo);
                s = s * __expf(m - nm) + so * __expf(mo - nm);
                m = nm;
            }
            if (mr == 0) {
                int row = m0 + wr * 64 + mt * 16 + kb * 4 + j;
                pm[(long)(nb * 2 + wc) * 1280 + row] = m;
                ps[(long)(nb * 2 + wc) * 1280 + row] = s;
            }
        }
}

// ---------------- final LSE reduce + NLL accumulate ----------------
__global__ __launch_bounds__(64) void k_lseb(const float* __restrict__ pm,
                                             const float* __restrict__ ps,
                                             const us* __restrict__ obf_all,
                                             const float* __restrict__ o2pW,
                                             const float* __restrict__ o2pb,
                                             const int* __restrict__ y,
                                             float* __restrict__ out) {
    int r = blockIdx.x, lane = threadIdx.x;
    int t = r >> 6, b = r & 63;
    int tgt = y[(t + 1) * 64 + b];
    float m = -1e30f, s = 0.f;
    for (int p = lane; p < 512; p += 64) {
        float mi = pm[(long)p * 1280 + r], si = ps[(long)p * 1280 + r];
        float nm = fmaxf(m, mi);
        s = s * __expf(m - nm) + si * __expf(mi - nm);
        m = nm;
    }
#pragma unroll
    for (int off = 32; off; off >>= 1) {
        float mo = __shfl_xor(m, off, 64), so = __shfl_xor(s, off, 64);
        float nm = fmaxf(m, mo);
        s = s * __expf(m - nm) + so * __expf(mo - nm);
        m = nm;
    }
    float d = 0.f;
    const float* wr = o2pW + (long)tgt * 512;
#pragma unroll
    for (int k = 0; k < 8; ++k)
        d += b2f(obf_all[(long)r * 512 + lane + k * 64]) * wr[lane + k * 64];
#pragma unroll
    for (int off = 32; off; off >>= 1) d += __shfl_xor(d, off, 64);
    if (lane == 0 && tgt != 0)
        atomicAdd(out, (m + __logf(s)) - (d + o2pb[tgt]));
}

extern "C" void kernel_launch(void* const* d_in, const int* in_sizes, int n_in,
                              void* d_out, int out_size, void* d_ws, size_t ws_size,
                              hipStream_t stream) {
    const float* ctx     = (const float*)d_in[0];
    const int*   y       = (const int*)d_in[1];
    const float* embW    = (const float*)d_in[2];
    const float* att_c2c = (const float*)d_in[3];
    const float* att_h2c = (const float*)d_in[4];
    const float* mlp     = (const float*)d_in[5];
    const float* Wih     = (const float*)d_in[6];
    const float* bih     = (const float*)d_in[7];
    const float* Whh     = (const float*)d_in[8];
    const float* bhh     = (const float*)d_in[9];
    const float* h2oW    = (const float*)d_in[10];
    const float* h2ob    = (const float*)d_in[11];
    const float* octxW   = (const float*)d_in[12];
    const float* octxb   = (const float*)d_in[13];
    const float* o2pW    = (const float*)d_in[14];
    const float* o2pb    = (const float*)d_in[15];
    float* out = (float*)d_out;

    char* base = (char*)d_ws;
    us* ctxbf   = (us*)base; base += 25690112L;   // [s][b][c] bf16 (= GEMM A)
    us* cpbf    = (us*)base; base += 25690112L;   // [12544][1024]; pm/ps alias after loop
    us* c2cT    = (us*)base; base += 2097152L;
    us* attbf   = (us*)base; base += 2097152L;
    us* Wg      = (us*)base; base += 15728640L;
    us* h2obf   = (us*)base; base += 1048576L;
    us* octxbf  = (us*)base; base += 1048576L;
    uc* o2p8    = (uc*)base; base += 16777216L;   // [32768][512] fp8, rows 32000+ zero
    us* xc      = (us*)base; base += 6225920L;    // [19][64][2560]
    us* ht_all  = (us*)base; base += 2621440L;    // [20*64][1024], rows 0..63 = h0 = 0
    us* obf_all = (us*)base; base += 1310720L;    // [1280][512] bf16, rows 1216+ pad
    uc* obf8    = (uc*)base; base += 655360L;     // [1280][512] fp8
    float* hf32   = (float*)base; base += 262144L;  // [64][1024]
    float* hpp    = (float*)base; base += 524288L;  // [2][64][1024]
    float* scb    = (float*)base; base += 50176L;   // [64][196]
    float* pm   = (float*)cpbf;                   // [512][1280] aliases cpbf (dead by then)
    float* ps   = pm + 655360L;

    (void)hipMemsetAsync(d_out, 0, sizeof(float), stream);
    (void)hipMemsetAsync(hf32, 0, 262144, stream);
    (void)hipMemsetAsync(ht_all, 0, 131072, stream);                 // h0 rows
    (void)hipMemsetAsync(obf_all + 1216L * 512, 0, 65536, stream);   // bf16 pad rows
    (void)hipMemsetAsync(obf8 + 1216L * 512, 0, 32768, stream);      // fp8 pad rows
    (void)hipMemsetAsync(o2p8 + 16384000L, 0, 393216, stream);       // weight pad rows
    (void)hipMemsetAsync(xc, 0, 6225920, stream);

    // prep
    k_yemb<<<TS_ * 64, 256, 0, stream>>>(y, embW, xc);
    k_tcvt<<<dim3(32, 32), dim3(32, 8), 0, stream>>>(att_c2c, c2cT);
    k_tcvt<<<dim3(32, 32), dim3(32, 8), 0, stream>>>(att_h2c, attbf);
    k_cvt<<<2048, 256, 0, stream>>>(ctx, ctxbf, 12845056L);
    k_cvt<<<512, 256, 0, stream>>>(h2oW, h2obf, 524288L);
    k_cvt<<<512, 256, 0, stream>>>(octxW, octxbf, 524288L);
    k_cvt8<<<2048, 256, 0, stream>>>(o2pW, o2p8, 16384000L);
    k_prepw<<<4096, 256, 0, stream>>>(Wih, Whh, Wg);
    k_gemm<<<784, 256, 0, stream>>>(ctxbf, c2cT, cpbf);

    // sequential recurrence: 4 kernels per step
    for (int t = 0; t < TS_; t++) {
        k_hproj<<<128, 256, 0, stream>>>(ht_all + (long)t * 65536, attbf, hpp);
        k_scores<<<256, 1024, 0, stream>>>(cpbf, hpp, mlp, scb);
        k_z<<<256, 512, 0, stream>>>(scb, ctxbf, xc, t);
        k_gruh2<<<256, 512, 0, stream>>>(xc, Wg, bih, bhh, hf32, ht_all, t);
    }

    // deferred output head, batched over all steps
    k_outb<<<dim3(19, 2), 256, 0, stream>>>(ht_all, xc, h2obf, h2ob, octxbf, octxb,
                                            obf_all, obf8);
    k_vocab8<<<2560, 256, 0, stream>>>(obf8, o2p8, o2pb, pm, ps);
    k_lseb<<<1216, 64, 0, stream>>>(pm, ps, obf_all, o2pW, o2pb, y, out);
}